// Round 1
// 1751.698 us; speedup vs baseline: 2.9688x; 2.9688x over previous
//
#include <hip/hip_runtime.h>

#define S_LEN 8192
#define HID   2048
#define NH    16
#define HD    128
#define BLKC  256
#define QKV_STRIDE 6144
#define EPSV  1e-5f
#define SCALEF 0.08838834764831845f

typedef unsigned short u16;
typedef __attribute__((ext_vector_type(8))) short bf16x8;
typedef __attribute__((ext_vector_type(4))) float f32x4;

__device__ __forceinline__ float b2f(u16 u) {
    unsigned int x = ((unsigned int)u) << 16;
    return __uint_as_float(x);
}
__device__ __forceinline__ u16 f2b(float f) {
    unsigned int u = __float_as_uint(f);
    u += 0x7fff + ((u >> 16) & 1);   // round-to-nearest-even
    return (u16)(u >> 16);
}
__device__ __forceinline__ float get_slope(int h) {
    return exp2f(-0.5f * (float)(h + 1)) * 1.00001f;
}

#define GLOAD_LDS16(g, l)                                              \
    __builtin_amdgcn_global_load_lds(                                  \
        (const __attribute__((address_space(1))) void*)(g),            \
        (__attribute__((address_space(3))) void*)(l), 16, 0, 0)

// ---------------------------------------------------------------------------
// Canonize one fp32 tensor to bf16.
// ---------------------------------------------------------------------------
__global__ __launch_bounds__(256) void canonize_kernel(const float* __restrict__ src,
                                                       u16* __restrict__ dst, int n) {
    const int i0 = (blockIdx.x * 256 + threadIdx.x) * 4;
    if (i0 >= n) return;
    const float4 f = *(const float4*)(src + i0);
    ushort4 o;
    o.x = f2b(f.x); o.y = f2b(f.y); o.z = f2b(f.z); o.w = f2b(f.w);
    *(ushort4*)(dst + i0) = o;
}

// ---------------------------------------------------------------------------
// MFMA GEMM: C[M][N] = A[M][K] @ B[N][K]^T (+bias). bf16 in, f32 accum.
// m97 structure: 128x128 tile, 4 waves (2x2 of 64x64), 4x4 16x16x32 frags,
// global_load_lds width-16 staging into linear LDS, 2 barriers per K-step.
// OUT_F32=0 -> bf16 C, OUT_F32=1 -> fp32 C.
// ---------------------------------------------------------------------------
template<int OUT_F32>
__global__ __launch_bounds__(256) void gemm_mfma(const u16* __restrict__ A,
                                                 const u16* __restrict__ B,
                                                 const u16* __restrict__ bias,
                                                 void* __restrict__ Cv,
                                                 int K, int lda, int ldb, int ldc) {
    __shared__ u16 As[128 * 32];
    __shared__ u16 Bs[128 * 32];
    const int t = threadIdx.x;
    const int w = t >> 6;            // wave 0..3
    const int l = t & 63;            // lane
    const int row0 = blockIdx.y << 7, col0 = blockIdx.x << 7;

    // --- staging layout: each call = 4KB (64 lanes x 4 waves x 16B).
    // element offset within a 4KB chunk: se = w*512 + l*8  ->  row = se/32, col = se%32
    const int se   = (w << 9) + (l << 3);
    const int srow = se >> 5;        // w*16 + l/4   (0..63 across the block)
    const int scol = se & 31;        // (l&3)*8
    const u16* Ap = A + (size_t)(row0 + srow) * lda + scol;
    const u16* Bp = B + (size_t)(col0 + srow) * ldb + scol;
    u16* AsP = As + se;              // lane's 16B slot; HW: wave-uniform base + lane*16
    u16* BsP = Bs + se;

    // --- wave's 64x64 output sub-tile
    const int wr = (w >> 1) << 6;    // 0 or 64
    const int wc = (w & 1) << 6;     // 0 or 64
    const int fr = l & 15;           // fragment row/col
    const int fk = (l >> 4) << 3;    // k-offset 0,8,16,24

    f32x4 acc[4][4] = {};

    for (int k0 = 0; k0 < K; k0 += 32) {
        __syncthreads();             // all waves done reading LDS
        GLOAD_LDS16(Ap + k0, AsP);
        GLOAD_LDS16(Ap + k0 + (size_t)64 * lda, AsP + 64 * 32);
        GLOAD_LDS16(Bp + k0, BsP);
        GLOAD_LDS16(Bp + k0 + (size_t)64 * ldb, BsP + 64 * 32);
        __syncthreads();             // compiler drains vmcnt(0) before barrier

        bf16x8 a[4], b[4];
#pragma unroll
        for (int m = 0; m < 4; ++m)
            a[m] = *(const bf16x8*)&As[(wr + (m << 4) + fr) * 32 + fk];
#pragma unroll
        for (int n = 0; n < 4; ++n)
            b[n] = *(const bf16x8*)&Bs[(wc + (n << 4) + fr) * 32 + fk];
#pragma unroll
        for (int m = 0; m < 4; ++m)
#pragma unroll
            for (int n = 0; n < 4; ++n)
                acc[m][n] = __builtin_amdgcn_mfma_f32_16x16x32_bf16(
                    a[m], b[n], acc[m][n], 0, 0, 0);
    }

    // --- epilogue: C/D layout col=lane&15, row=(lane>>4)*4+reg
    const int crow = row0 + wr + ((l >> 4) << 2);
    const int ccol = col0 + wc + fr;
#pragma unroll
    for (int n = 0; n < 4; ++n) {
        const float bv = (bias != nullptr) ? b2f(bias[ccol + (n << 4)]) : 0.f;
#pragma unroll
        for (int m = 0; m < 4; ++m) {
#pragma unroll
            for (int r = 0; r < 4; ++r) {
                const float val = acc[m][n][r] + bv;
                const size_t off = (size_t)(crow + (m << 4) + r) * ldc + ccol + (n << 4);
                if (OUT_F32) ((float*)Cv)[off] = val;
                else         ((u16*)Cv)[off]   = f2b(val);
            }
        }
    }
}

// ---------------------------------------------------------------------------
// Per (local row, head): RMSNorm(q,k) -> RoPE -> q*=SCALE. In place.
// ---------------------------------------------------------------------------
__global__ __launch_bounds__(128) void normrope_kernel(u16* __restrict__ qkvb,
                                                       const u16* __restrict__ qw,
                                                       const u16* __restrict__ kw,
                                                       const int* __restrict__ pos,
                                                       int row0) {
    const int b = blockIdx.x;
    const int s = b >> 4, h = b & 15;
    const int d = threadIdx.x;
    u16* qp = qkvb + (size_t)s * QKV_STRIDE + h * HD + d;
    u16* kp = qp + HID;
    const float q = b2f(*qp), k = b2f(*kp);
    __shared__ float red[128], sq[128], sk[128];
    red[d] = q * q;
    __syncthreads();
    for (int off = 64; off > 0; off >>= 1) {
        if (d < off) red[d] += red[d + off];
        __syncthreads();
    }
    const float qr = rsqrtf(red[0] * (1.f / 128.f) + EPSV);
    __syncthreads();
    red[d] = k * k;
    __syncthreads();
    for (int off = 64; off > 0; off >>= 1) {
        if (d < off) red[d] += red[d + off];
        __syncthreads();
    }
    const float kr = rsqrtf(red[0] * (1.f / 128.f) + EPSV);
    sq[d] = q * qr * b2f(qw[d]);
    sk[d] = k * kr * b2f(kw[d]);
    __syncthreads();
    const int p = pos[row0 + s];
    const int t2 = d & 63;
    const float invf = powf(600000.f, -(float)t2 * (1.f / 64.f));
    const float fr = (float)p * invf;
    const float cs = cosf(fr), sn = sinf(fr);
    float oq, ok;
    if (d < 64) {
        oq = sq[d] * cs - sq[d + 64] * sn;
        ok = sk[d] * cs - sk[d + 64] * sn;
    } else {
        oq = sq[d] * cs + sq[d - 64] * sn;
        ok = sk[d] * cs + sk[d - 64] * sn;
    }
    *qp = f2b(oq * SCALEF);
    *kp = f2b(ok);
}

// ---------------------------------------------------------------------------
// Per (local chunk, head): contrib[d][e] = sum_j exp(-slope*(255-j)) k[j][d] v[j][e]
// ---------------------------------------------------------------------------
__global__ __launch_bounds__(256) void kv_contrib_kernel(const u16* __restrict__ qkvb,
                                                         float* __restrict__ contrib) {
    const int b = blockIdx.x;
    const int c = b >> 4, h = b & 15;
    const float slope = get_slope(h);
    const u16* kb = qkvb + (size_t)c * BLKC * QKV_STRIDE + HID + h * HD;
    const u16* vb = kb + HID;
    const int t = threadIdx.x;
    const int tx = t & 15, ty = t >> 4;
    const int jj = t >> 5, dd = (t & 31) << 2;
    float acc[8][8] = {};
    __shared__ float kf[8][128], vf[8][128];
    for (int j0 = 0; j0 < BLKC; j0 += 8) {
        const float kd = expf(-slope * (float)(BLKC - 1 - (j0 + jj)));
        ushort4 k4 = *(const ushort4*)(kb + (size_t)(j0 + jj) * QKV_STRIDE + dd);
        ushort4 v4 = *(const ushort4*)(vb + (size_t)(j0 + jj) * QKV_STRIDE + dd);
        kf[jj][dd + 0] = b2f(k4.x) * kd; kf[jj][dd + 1] = b2f(k4.y) * kd;
        kf[jj][dd + 2] = b2f(k4.z) * kd; kf[jj][dd + 3] = b2f(k4.w) * kd;
        vf[jj][dd + 0] = b2f(v4.x); vf[jj][dd + 1] = b2f(v4.y);
        vf[jj][dd + 2] = b2f(v4.z); vf[jj][dd + 3] = b2f(v4.w);
        __syncthreads();
#pragma unroll
        for (int j = 0; j < 8; ++j) {
            float4 k0 = *(const float4*)&kf[j][ty << 3];
            float4 k1 = *(const float4*)&kf[j][(ty << 3) + 4];
            float4 v0 = *(const float4*)&vf[j][tx << 3];
            float4 v1 = *(const float4*)&vf[j][(tx << 3) + 4];
            float kr[8] = {k0.x, k0.y, k0.z, k0.w, k1.x, k1.y, k1.z, k1.w};
            float vr[8] = {v0.x, v0.y, v0.z, v0.w, v1.x, v1.y, v1.z, v1.w};
#pragma unroll
            for (int u = 0; u < 8; ++u)
#pragma unroll
                for (int v = 0; v < 8; ++v) acc[u][v] += kr[u] * vr[v];
        }
        __syncthreads();
    }
    float* cb = contrib + ((size_t)(c * NH + h) * HD + (ty << 3)) * HD + (tx << 3);
#pragma unroll
    for (int u = 0; u < 8; ++u) {
        *(float4*)(cb + (size_t)u * HD)     = make_float4(acc[u][0], acc[u][1], acc[u][2], acc[u][3]);
        *(float4*)(cb + (size_t)u * HD + 4) = make_float4(acc[u][4], acc[u][5], acc[u][6], acc[u][7]);
    }
}

// ---------------------------------------------------------------------------
// Scan with carry across super-chunks.
// ---------------------------------------------------------------------------
__global__ __launch_bounds__(256) void kv_scan_kernel(float* __restrict__ buf,
                                                      float* __restrict__ carry,
                                                      int ncs) {
    const int tid = blockIdx.x * 256 + threadIdx.x;   // < NH*HD*HD = 262144
    const int h = tid >> 14;
    const float bd = expf(-get_slope(h) * (float)BLKC);
    float prev = carry[tid];
    for (int c = 0; c < ncs; ++c) {
        const size_t off = (size_t)c * (NH * HD * HD) + tid;
        const float cur = buf[off];
        buf[off] = prev;
        prev = bd * prev + cur;
    }
    carry[tid] = prev;
}

// ---------------------------------------------------------------------------
// Per (local chunk, head, i-tile of 32): intra (QK^T*decay)@V + inter.
// Output in place into the q-slot (own Q tile staged to LDS first).
// ---------------------------------------------------------------------------
__global__ __launch_bounds__(256) void attn_kernel(u16* __restrict__ qkvb,
                                                   const float* __restrict__ kvstates) {
    const int b  = blockIdx.x;
    const int it = b & 7;
    const int h  = (b >> 3) & 15;
    const int c  = b >> 7;
    const float slope = get_slope(h);
    const int t = threadIdx.x;
    const int tx = t & 15, ty = t >> 4;
    __shared__ float qf[32][132], kf[32][132], vf[32][132], Sc[32][36];
    u16* qb = qkvb + (size_t)(c * BLKC + it * 32) * QKV_STRIDE + h * HD;
#pragma unroll
    for (int u = 0; u < 2; ++u) {
        int fi = t + (u << 8);
        int r = fi >> 4, c8 = (fi & 15) << 3;
        int4 raw = *(const int4*)(qb + (size_t)r * QKV_STRIDE + c8);
        const u16* pr = (const u16*)&raw;
#pragma unroll
        for (int x = 0; x < 8; ++x) qf[r][c8 + x] = b2f(pr[x]);
    }
    float acc[2][8]  = {};
    float acc2[2][8] = {};
    const int i0 = ty << 1, j0 = tx << 1;
    for (int jt = 0; jt <= it; ++jt) {
        const u16* kb = qkvb + (size_t)(c * BLKC + jt * 32) * QKV_STRIDE + HID + h * HD;
        const u16* vb = kb + HID;
        __syncthreads();
#pragma unroll
        for (int u = 0; u < 2; ++u) {
            int fi = t + (u << 8);
            int r = fi >> 4, c8 = (fi & 15) << 3;
            int4 kraw = *(const int4*)(kb + (size_t)r * QKV_STRIDE + c8);
            int4 vraw = *(const int4*)(vb + (size_t)r * QKV_STRIDE + c8);
            const u16* kpr = (const u16*)&kraw;
            const u16* vpr = (const u16*)&vraw;
#pragma unroll
            for (int x = 0; x < 8; ++x) {
                kf[r][c8 + x] = b2f(kpr[x]);
                vf[r][c8 + x] = b2f(vpr[x]);
            }
        }
        __syncthreads();
        float s00 = 0.f, s01 = 0.f, s10 = 0.f, s11 = 0.f;
#pragma unroll 8
        for (int d0 = 0; d0 < HD; d0 += 4) {
            float4 qa = *(const float4*)&qf[i0][d0];
            float4 qc = *(const float4*)&qf[i0 + 1][d0];
            float4 ka = *(const float4*)&kf[j0][d0];
            float4 kc = *(const float4*)&kf[j0 + 1][d0];
            s00 += qa.x * ka.x + qa.y * ka.y + qa.z * ka.z + qa.w * ka.w;
            s01 += qa.x * kc.x + qa.y * kc.y + qa.z * kc.z + qa.w * kc.w;
            s10 += qc.x * ka.x + qc.y * ka.y + qc.z * ka.z + qc.w * ka.w;
            s11 += qc.x * kc.x + qc.y * kc.y + qc.z * kc.z + qc.w * kc.w;
        }
        const int ig = it * 32 + i0, jg = jt * 32 + j0;
        const int d00i = ig - jg     > 0 ? ig - jg     : 0;
        const int d01i = ig - jg - 1 > 0 ? ig - jg - 1 : 0;
        const int d10i = ig - jg + 1 > 0 ? ig - jg + 1 : 0;
        const float e00 = expf(-slope * (float)d00i);
        const float e01 = expf(-slope * (float)d01i);
        const float e10 = expf(-slope * (float)d10i);
        Sc[i0][j0]         = (ig     >= jg    ) ? s00 * e00 : 0.f;
        Sc[i0][j0 + 1]     = (ig     >= jg + 1) ? s01 * e01 : 0.f;
        Sc[i0 + 1][j0]     = (ig + 1 >= jg    ) ? s10 * e10 : 0.f;
        Sc[i0 + 1][j0 + 1] = (ig + 1 >= jg + 1) ? s11 * e00 : 0.f;
        __syncthreads();
#pragma unroll
        for (int j = 0; j < 32; ++j) {
            const float sa = Sc[i0][j], sb = Sc[i0 + 1][j];
            float4 v0 = *(const float4*)&vf[j][tx << 3];
            float4 v1 = *(const float4*)&vf[j][(tx << 3) + 4];
            float vv[8] = {v0.x, v0.y, v0.z, v0.w, v1.x, v1.y, v1.z, v1.w};
#pragma unroll
            for (int e = 0; e < 8; ++e) {
                acc[0][e] += sa * vv[e];
                acc[1][e] += sb * vv[e];
            }
        }
    }
    const float* kvb = kvstates + (size_t)(c * NH + h) * (HD * HD);
    for (int dt = 0; dt < 4; ++dt) {
        __syncthreads();
#pragma unroll
        for (int u = 0; u < 4; ++u) {
            int fi = t + (u << 8);
            int r = fi >> 5, c4 = (fi & 31) << 2;
            *(float4*)&kf[r][c4] = *(const float4*)(kvb + (size_t)(dt * 32 + r) * HD + c4);
        }
        __syncthreads();
#pragma unroll
        for (int dd = 0; dd < 32; ++dd) {
            const float qa = qf[i0][dt * 32 + dd];
            const float qc = qf[i0 + 1][dt * 32 + dd];
            float4 v0 = *(const float4*)&kf[dd][tx << 3];
            float4 v1 = *(const float4*)&kf[dd][(tx << 3) + 4];
            float vv[8] = {v0.x, v0.y, v0.z, v0.w, v1.x, v1.y, v1.z, v1.w};
#pragma unroll
            for (int e = 0; e < 8; ++e) {
                acc2[0][e] += qa * vv[e];
                acc2[1][e] += qc * vv[e];
            }
        }
    }
    const float qd[2] = {expf(-slope * (float)(it * 32 + i0 + 1)),
                         expf(-slope * (float)(it * 32 + i0 + 2))};
    u16* op = qb + (tx << 3);
#pragma unroll
    for (int a = 0; a < 2; ++a) {
        ushort4 o1, o2;
        float ov[8];
#pragma unroll
        for (int e = 0; e < 8; ++e) ov[e] = acc[a][e] + qd[a] * acc2[a][e];
        o1.x = f2b(ov[0]); o1.y = f2b(ov[1]); o1.z = f2b(ov[2]); o1.w = f2b(ov[3]);
        o2.x = f2b(ov[4]); o2.y = f2b(ov[5]); o2.z = f2b(ov[6]); o2.w = f2b(ov[7]);
        *(ushort4*)(op + (size_t)(i0 + a) * QKV_STRIDE)     = o1;
        *(ushort4*)(op + (size_t)(i0 + a) * QKV_STRIDE + 4) = o2;
    }
}

// ---------------------------------------------------------------------------
// Group RMSNorm * g_norm_w * sigmoid(g): q-slot x k-slot -> v-slot.
// ---------------------------------------------------------------------------
__global__ __launch_bounds__(256) void gate_kernel(u16* __restrict__ qkvb,
                                                   const u16* __restrict__ gnw) {
    const int b = blockIdx.x;
    const int s = b >> 3, grp = b & 7;
    const int t = threadIdx.x;
    const int j = (grp << 8) + t;
    const size_t base = (size_t)s * QKV_STRIDE;
    const float x = b2f(qkvb[base + j]);
    __shared__ float red[256];
    red[t] = x * x;
    __syncthreads();
    for (int off = 128; off > 0; off >>= 1) {
        if (t < off) red[t] += red[t + off];
        __syncthreads();
    }
    const float rstd = rsqrtf(red[0] * (1.f / 256.f) + EPSV);
    const float gv = b2f(qkvb[base + HID + j]);
    const float yv = x * rstd * b2f(gnw[j]) * (1.f / (1.f + expf(-gv)));
    qkvb[base + 2 * HID + j] = f2b(yv);
}

// ---------------------------------------------------------------------------
extern "C" void kernel_launch(void* const* d_in, const int* in_sizes, int n_in,
                              void* d_out, int out_size, void* d_ws, size_t ws_size,
                              hipStream_t stream) {
    const int* pos = (const int*)d_in[1];
    float* out = (float*)d_out;   // reference output dtype: float32
    char* ws = (char*)d_ws;

    // ---- canonical bf16 input area -------------------------------------
    u16*  c_hs    = (u16*)(ws + 256);                 // 16777216 el
    u16*  c_qkvw  = c_hs   + 16777216;                // 12582912 el
    u16*  c_qkvb  = c_qkvw + 12582912;                // 6144
    u16*  c_qn    = c_qkvb + 6144;                    // 128
    u16*  c_kn    = c_qn   + 128;                     // 128
    u16*  c_gw    = c_kn   + 128;                     // 4194304
    u16*  c_gnw   = c_gw   + 4194304;                 // 2048
    u16*  c_dw    = c_gnw  + 2048;                    // 4194304
    const size_t canon_end = 256 + (size_t)2 * (16777216 + 12582912 + 6144 + 128 + 128 + 4194304 + 2048 + 4194304);
    const size_t work_off = (canon_end + 255) & ~(size_t)255;

    // ---- pick super-chunk size to fit ws -------------------------------
    const size_t MB = 1048576;
    int SCR;
    if      (ws_size >= work_off + (size_t)2048 * QKV_STRIDE * 2 + 9 * MB) SCR = 2048;
    else if (ws_size >= work_off + (size_t)512  * QKV_STRIDE * 2 + 3 * MB) SCR = 512;
    else                                                                    SCR = 256;
    const int NCS = SCR / BLKC;
    const int NSC = S_LEN / SCR;

    u16*   qkvb   = (u16*)(ws + work_off);
    float* states = (float*)(ws + work_off + (size_t)SCR * QKV_STRIDE * 2);
    float* carry  = states + (size_t)NCS * NH * HD * HD;

    const dim3 B256(256);

    // 0) canonize all fp32 float inputs to bf16
    canonize_kernel<<<dim3(16777216 / 1024), B256, 0, stream>>>((const float*)d_in[0], c_hs,   16777216);
    canonize_kernel<<<dim3(12582912 / 1024), B256, 0, stream>>>((const float*)d_in[2], c_qkvw, 12582912);
    canonize_kernel<<<dim3(6),               B256, 0, stream>>>((const float*)d_in[3], c_qkvb, 6144);
    canonize_kernel<<<dim3(1),               B256, 0, stream>>>((const float*)d_in[4], c_qn,   128);
    canonize_kernel<<<dim3(1),               B256, 0, stream>>>((const float*)d_in[5], c_kn,   128);
    canonize_kernel<<<dim3(4194304 / 1024),  B256, 0, stream>>>((const float*)d_in[6], c_gw,   4194304);
    canonize_kernel<<<dim3(2),               B256, 0, stream>>>((const float*)d_in[7], c_gnw,  2048);
    canonize_kernel<<<dim3(4194304 / 1024),  B256, 0, stream>>>((const float*)d_in[8], c_dw,   4194304);

    hipMemsetAsync(carry, 0, (size_t)NH * HD * HD * sizeof(float), stream);

    for (int sc = 0; sc < NSC; ++sc) {
        const int row0 = sc * SCR;
        const u16* hsb = c_hs + (size_t)row0 * HID;
        gemm_mfma<0><<<dim3(QKV_STRIDE / 128, SCR / 128), B256, 0, stream>>>(
            hsb, c_qkvw, c_qkvb, qkvb, HID, HID, HID, QKV_STRIDE);
        normrope_kernel<<<dim3(SCR * NH), dim3(128), 0, stream>>>(
            qkvb, c_qn, c_kn, pos, row0);
        kv_contrib_kernel<<<dim3(NCS * NH), B256, 0, stream>>>(qkvb, states);
        kv_scan_kernel<<<dim3(NH * HD * HD / 256), B256, 0, stream>>>(states, carry, NCS);
        attn_kernel<<<dim3(NCS * NH * 8), B256, 0, stream>>>(qkvb, states);
        gemm_mfma<0><<<dim3(HID / 128, SCR / 128), B256, 0, stream>>>(
            hsb, c_gw, nullptr, qkvb + HID, HID, HID, HID, QKV_STRIDE);
        gate_kernel<<<dim3(SCR * 8), B256, 0, stream>>>(qkvb, c_gnw);
        gemm_mfma<1><<<dim3(HID / 128, SCR / 128), B256, 0, stream>>>(
            qkvb + 2 * HID, c_dw, nullptr, out + (size_t)row0 * HID,
            HID, QKV_STRIDE, HID, HID);
    }
}

// Round 3
// 1291.784 us; speedup vs baseline: 4.0258x; 1.3560x over previous
//
#include <hip/hip_runtime.h>

#define S_LEN 8192
#define HID   2048
#define NH    16
#define HD    128
#define BLKC  256
#define QKV_STRIDE 6144
#define EPSV  1e-5f
#define SCALEF 0.08838834764831845f

typedef unsigned short u16;
typedef unsigned int   u32;
typedef __attribute__((ext_vector_type(8))) short bf16x8;
typedef __attribute__((ext_vector_type(4))) float f32x4;

__device__ __forceinline__ float b2f(u16 u) {
    unsigned int x = ((unsigned int)u) << 16;
    return __uint_as_float(x);
}
__device__ __forceinline__ u16 f2b(float f) {
    unsigned int u = __float_as_uint(f);
    u += 0x7fff + ((u >> 16) & 1);   // round-to-nearest-even
    return (u16)(u >> 16);
}
__device__ __forceinline__ u32 pack2(float lo, float hi) {
    return (u32)f2b(lo) | ((u32)f2b(hi) << 16);
}
__device__ __forceinline__ float get_slope(int h) {
    return exp2f(-0.5f * (float)(h + 1)) * 1.00001f;
}

#define GLOAD_LDS16(g, l)                                              \
    __builtin_amdgcn_global_load_lds(                                  \
        (const __attribute__((address_space(1))) void*)(g),            \
        (__attribute__((address_space(3))) void*)(l), 16, 0, 0)

// ---------------------------------------------------------------------------
// Canonize one fp32 tensor to bf16.
// ---------------------------------------------------------------------------
__global__ __launch_bounds__(256) void canonize_kernel(const float* __restrict__ src,
                                                       u16* __restrict__ dst, int n) {
    const int i0 = (blockIdx.x * 256 + threadIdx.x) * 4;
    if (i0 >= n) return;
    const float4 f = *(const float4*)(src + i0);
    ushort4 o;
    o.x = f2b(f.x); o.y = f2b(f.y); o.z = f2b(f.z); o.w = f2b(f.w);
    *(ushort4*)(dst + i0) = o;
}

// ---------------------------------------------------------------------------
// MFMA GEMM: C[M][N] = A[M][K] @ B[N][K]^T (+bias). bf16 in, f32 accum.
// ---------------------------------------------------------------------------
template<int OUT_F32>
__global__ __launch_bounds__(256) void gemm_mfma(const u16* __restrict__ A,
                                                 const u16* __restrict__ B,
                                                 const u16* __restrict__ bias,
                                                 void* __restrict__ Cv,
                                                 int K, int lda, int ldb, int ldc) {
    __shared__ u16 As[128 * 32];
    __shared__ u16 Bs[128 * 32];
    const int t = threadIdx.x;
    const int w = t >> 6;
    const int l = t & 63;
    const int row0 = blockIdx.y << 7, col0 = blockIdx.x << 7;

    const int se   = (w << 9) + (l << 3);
    const int srow = se >> 5;
    const int scol = se & 31;
    const u16* Ap = A + (size_t)(row0 + srow) * lda + scol;
    const u16* Bp = B + (size_t)(col0 + srow) * ldb + scol;
    u16* AsP = As + se;
    u16* BsP = Bs + se;

    const int wr = (w >> 1) << 6;
    const int wc = (w & 1) << 6;
    const int fr = l & 15;
    const int fk = (l >> 4) << 3;

    f32x4 acc[4][4] = {};

    for (int k0 = 0; k0 < K; k0 += 32) {
        __syncthreads();
        GLOAD_LDS16(Ap + k0, AsP);
        GLOAD_LDS16(Ap + k0 + (size_t)64 * lda, AsP + 64 * 32);
        GLOAD_LDS16(Bp + k0, BsP);
        GLOAD_LDS16(Bp + k0 + (size_t)64 * ldb, BsP + 64 * 32);
        __syncthreads();

        bf16x8 a[4], b[4];
#pragma unroll
        for (int m = 0; m < 4; ++m)
            a[m] = *(const bf16x8*)&As[(wr + (m << 4) + fr) * 32 + fk];
#pragma unroll
        for (int n = 0; n < 4; ++n)
            b[n] = *(const bf16x8*)&Bs[(wc + (n << 4) + fr) * 32 + fk];
#pragma unroll
        for (int m = 0; m < 4; ++m)
#pragma unroll
            for (int n = 0; n < 4; ++n)
                acc[m][n] = __builtin_amdgcn_mfma_f32_16x16x32_bf16(
                    a[m], b[n], acc[m][n], 0, 0, 0);
    }

    const int crow = row0 + wr + ((l >> 4) << 2);
    const int ccol = col0 + wc + fr;
#pragma unroll
    for (int n = 0; n < 4; ++n) {
        const float bv = (bias != nullptr) ? b2f(bias[ccol + (n << 4)]) : 0.f;
#pragma unroll
        for (int m = 0; m < 4; ++m) {
#pragma unroll
            for (int r = 0; r < 4; ++r) {
                const float val = acc[m][n][r] + bv;
                const size_t off = (size_t)(crow + (m << 4) + r) * ldc + ccol + (n << 4);
                if (OUT_F32) ((float*)Cv)[off] = val;
                else         ((u16*)Cv)[off]   = f2b(val);
            }
        }
    }
}

// ---------------------------------------------------------------------------
// Per (local row, head): RMSNorm(q,k) -> RoPE -> q*=SCALE. In place.
// ---------------------------------------------------------------------------
__global__ __launch_bounds__(128) void normrope_kernel(u16* __restrict__ qkvb,
                                                       const u16* __restrict__ qw,
                                                       const u16* __restrict__ kw,
                                                       const int* __restrict__ pos,
                                                       int row0) {
    const int b = blockIdx.x;
    const int s = b >> 4, h = b & 15;
    const int d = threadIdx.x;
    u16* qp = qkvb + (size_t)s * QKV_STRIDE + h * HD + d;
    u16* kp = qp + HID;
    const float q = b2f(*qp), k = b2f(*kp);
    __shared__ float red[128], sq[128], sk[128];
    red[d] = q * q;
    __syncthreads();
    for (int off = 64; off > 0; off >>= 1) {
        if (d < off) red[d] += red[d + off];
        __syncthreads();
    }
    const float qr = rsqrtf(red[0] * (1.f / 128.f) + EPSV);
    __syncthreads();
    red[d] = k * k;
    __syncthreads();
    for (int off = 64; off > 0; off >>= 1) {
        if (d < off) red[d] += red[d + off];
        __syncthreads();
    }
    const float kr = rsqrtf(red[0] * (1.f / 128.f) + EPSV);
    sq[d] = q * qr * b2f(qw[d]);
    sk[d] = k * kr * b2f(kw[d]);
    __syncthreads();
    const int p = pos[row0 + s];
    const int t2 = d & 63;
    const float invf = powf(600000.f, -(float)t2 * (1.f / 64.f));
    const float fr = (float)p * invf;
    const float cs = cosf(fr), sn = sinf(fr);
    float oq, ok;
    if (d < 64) {
        oq = sq[d] * cs - sq[d + 64] * sn;
        ok = sk[d] * cs - sk[d + 64] * sn;
    } else {
        oq = sq[d] * cs + sq[d - 64] * sn;
        ok = sk[d] * cs + sk[d - 64] * sn;
    }
    *qp = f2b(oq * SCALEF);
    *kp = f2b(ok);
}

// ---------------------------------------------------------------------------
// Per (local chunk, head): contribT[e][d] = sum_j exp(-slope*(255-j)) k[j][d] v[j][e]
// (TRANSPOSED output: [e][d] so attn's inter-MFMA reads KV^T row-major.)
// ---------------------------------------------------------------------------
__global__ __launch_bounds__(256) void kv_contrib_kernel(const u16* __restrict__ qkvb,
                                                         float* __restrict__ contrib) {
    const int b = blockIdx.x;
    const int c = b >> 4, h = b & 15;
    const float slope = get_slope(h);
    const u16* kb = qkvb + (size_t)c * BLKC * QKV_STRIDE + HID + h * HD;
    const u16* vb = kb + HID;
    const int t = threadIdx.x;
    const int tx = t & 15, ty = t >> 4;
    const int jj = t >> 5, dd = (t & 31) << 2;
    float acc[8][8] = {};
    __shared__ float kf[8][128], vf[8][128];
    for (int j0 = 0; j0 < BLKC; j0 += 8) {
        const float kd = expf(-slope * (float)(BLKC - 1 - (j0 + jj)));
        ushort4 k4 = *(const ushort4*)(kb + (size_t)(j0 + jj) * QKV_STRIDE + dd);
        ushort4 v4 = *(const ushort4*)(vb + (size_t)(j0 + jj) * QKV_STRIDE + dd);
        kf[jj][dd + 0] = b2f(k4.x) * kd; kf[jj][dd + 1] = b2f(k4.y) * kd;
        kf[jj][dd + 2] = b2f(k4.z) * kd; kf[jj][dd + 3] = b2f(k4.w) * kd;
        vf[jj][dd + 0] = b2f(v4.x); vf[jj][dd + 1] = b2f(v4.y);
        vf[jj][dd + 2] = b2f(v4.z); vf[jj][dd + 3] = b2f(v4.w);
        __syncthreads();
#pragma unroll
        for (int j = 0; j < 8; ++j) {
            float4 e0 = *(const float4*)&vf[j][ty << 3];
            float4 e1 = *(const float4*)&vf[j][(ty << 3) + 4];
            float4 d0 = *(const float4*)&kf[j][tx << 3];
            float4 d1 = *(const float4*)&kf[j][(tx << 3) + 4];
            float er[8] = {e0.x, e0.y, e0.z, e0.w, e1.x, e1.y, e1.z, e1.w};
            float dr[8] = {d0.x, d0.y, d0.z, d0.w, d1.x, d1.y, d1.z, d1.w};
#pragma unroll
            for (int u = 0; u < 8; ++u)
#pragma unroll
                for (int v = 0; v < 8; ++v) acc[u][v] += er[u] * dr[v];
        }
        __syncthreads();
    }
    float* cb = contrib + ((size_t)(c * NH + h) * HD + (ty << 3)) * HD + (tx << 3);
#pragma unroll
    for (int u = 0; u < 8; ++u) {
        *(float4*)(cb + (size_t)u * HD)     = make_float4(acc[u][0], acc[u][1], acc[u][2], acc[u][3]);
        *(float4*)(cb + (size_t)u * HD + 4) = make_float4(acc[u][4], acc[u][5], acc[u][6], acc[u][7]);
    }
}

// ---------------------------------------------------------------------------
// Scan with carry across super-chunks. Reads f32 contribs; emits the
// state-before-chunk-c as BF16 into bufb (attn consumes bf16 directly).
// ---------------------------------------------------------------------------
__global__ __launch_bounds__(256) void kv_scan_kernel(const float* __restrict__ buf,
                                                      u16* __restrict__ bufb,
                                                      float* __restrict__ carry,
                                                      int ncs) {
    const int tid = blockIdx.x * 256 + threadIdx.x;   // < NH*HD*HD = 262144
    const int h = tid >> 14;
    const float bd = expf(-get_slope(h) * (float)BLKC);
    float prev = carry[tid];
    for (int c = 0; c < ncs; ++c) {
        const size_t off = (size_t)c * (NH * HD * HD) + tid;
        const float cur = buf[off];
        bufb[off] = f2b(prev);
        prev = bd * prev + cur;
    }
    carry[tid] = prev;
}

// ---------------------------------------------------------------------------
// MFMA attention. Block = (chunk, head, row-half). 4 waves x 32 q-rows.
//   intra: S = QK^T (MFMA), decay+mask in-reg, S->bf16 pack into a per-wave
//          swizzled bounce buffer, then S@V (MFMA) with V^T staged in LDS
//          under a permuted k-order sigma(p): j = (p&1)*16 + (p>>1).
//   inter: (Q * qdecay) @ KV^T (MFMA) from bf16 transposed states.
// ---------------------------------------------------------------------------
__global__ __launch_bounds__(256) void attn_mfma_kernel(u16* __restrict__ qkvb,
                                                        const u16* __restrict__ kvstatesb) {
    const int b  = blockIdx.x;
    const int hb = b & 1;
    const int h  = (b >> 1) & 15;
    const int c  = b >> 5;
    const float slope = get_slope(h);
    const int t  = threadIdx.x;
    const int w  = t >> 6, l = t & 63;
    const int lg = l >> 4, lc = l & 15;
    const int giw = hb * 4 + w;          // global i-tile 0..7
    const int i0  = giw << 5;            // row base within chunk

    __shared__ u16 Ks[32 * 128];         // swizzled K tile: slot' = slot ^ (j&7)
    __shared__ u16 Vt[128 * 40];         // Vt[e][p] sigma-permuted, stride 40
    __shared__ u16 Sb[4 * 1024];         // per-wave 32x16-u32 bounce (2KB each)

    // ---- Q fragments (A-layout): rows i0+m*16+lc, k-slice kk*32+lg*8 ----
    const u16* qbase = qkvb + (size_t)(c * BLKC) * QKV_STRIDE + h * HD;
    bf16x8 qa[2][4];
#pragma unroll
    for (int m = 0; m < 2; ++m)
#pragma unroll
        for (int kk = 0; kk < 4; ++kk)
            qa[m][kk] = *(const bf16x8*)(qbase +
                (size_t)(i0 + m * 16 + lc) * QKV_STRIDE + kk * 32 + lg * 8);

    f32x4 acc[2][8] = {};

    const u16* kbase = qkvb + (size_t)(c * BLKC) * QKV_STRIDE + HID + h * HD;
    const u16* vbase = kbase + HID;
    const int jtmax = hb * 4 + 4;
    const int ve  = t & 127;             // e-row for V gather
    const int vph = t >> 7;              // phase: p0 = 0/8
    u16* SbW = Sb + (w << 10);

    for (int jt = 0; jt < jtmax; ++jt) {
        __syncthreads();
        // -- stage K: linear LDS dest, pre-swizzled global source --
#pragma unroll
        for (int u = 0; u < 2; ++u) {
            const int idx = t + (u << 8);
            const int j = idx >> 4, s = idx & 15;
            const int sp = s ^ (j & 7);
            GLOAD_LDS16(kbase + (size_t)(jt * 32 + j) * QKV_STRIDE + sp * 8,
                        Ks + idx * 8);
        }
        // -- gather V^T (coalesced 2B global loads, b128 LDS writes) --
        union { int4 q; u16 e[8]; } vv[2];
#pragma unroll
        for (int u = 0; u < 2; ++u) {
            const int p0 = vph * 8 + u * 16;
#pragma unroll
            for (int x = 0; x < 8; ++x) {
                const int p = p0 + x;
                const int j = ((p & 1) << 4) | (p >> 1);
                vv[u].e[x] = vbase[(size_t)(jt * 32 + j) * QKV_STRIDE + ve];
            }
        }
#pragma unroll
        for (int u = 0; u < 2; ++u) {
            const int p0 = vph * 8 + u * 16;
            *(int4*)&Vt[ve * 40 + p0] = vv[u].q;
        }
        __syncthreads();

        if (jt <= giw) {
            // -- QK^T --
            f32x4 sacc[2][2] = {};
#pragma unroll
            for (int kk = 0; kk < 4; ++kk) {
#pragma unroll
                for (int nj = 0; nj < 2; ++nj) {
                    const int j = nj * 16 + lc;
                    const int sp = (kk * 4 + lg) ^ (j & 7);
                    bf16x8 kf = *(const bf16x8*)&Ks[j * 128 + sp * 8];
#pragma unroll
                    for (int m = 0; m < 2; ++m)
                        sacc[m][nj] = __builtin_amdgcn_mfma_f32_16x16x32_bf16(
                            qa[m][kk], kf, sacc[m][nj], 0, 0, 0);
                }
            }
            // -- decay + mask + pack into per-wave swizzled bounce --
            const int di0 = i0 - jt * 32;
            const float cj0 = expf(slope * (float)lc);
            const float cj1 = expf(slope * (float)(16 + lc));
            const bool diag = (jt == giw);
#pragma unroll
            for (int m = 0; m < 2; ++m) {
#pragma unroll
                for (int r = 0; r < 4; ++r) {
                    const int irel = m * 16 + lg * 4 + r;     // i - i0
                    const float rex = expf(-slope * (float)(di0 + irel));
                    float v0 = sacc[m][0][r] * rex * cj0;
                    float v1 = sacc[m][1][r] * rex * cj1;
                    if (diag) {
                        if (irel < lc)      v0 = 0.f;
                        if (irel < 16 + lc) v1 = 0.f;
                    }
                    const u32 pk = pack2(v0, v1);
                    const int iL = irel;
                    const int rp = iL ^ ((iL >> 2) & 1);
                    *(u32*)&SbW[rp * 32 + ((lc << 1) ^ (((iL >> 2) & 3) << 3))] = pk;
                }
            }
            // -- read S as A-frags, SV MFMA --
            bf16x8 sA[2];
#pragma unroll
            for (int m = 0; m < 2; ++m) {
                const int iL = m * 16 + lc;
                const int rp = iL ^ ((iL >> 2) & 1);
                sA[m] = *(const bf16x8*)&SbW[rp * 32 + ((lg << 3) ^ (((iL >> 2) & 3) << 3))];
            }
#pragma unroll
            for (int ne = 0; ne < 8; ++ne) {
                bf16x8 vf = *(const bf16x8*)&Vt[(ne * 16 + lc) * 40 + lg * 8];
#pragma unroll
                for (int m = 0; m < 2; ++m)
                    acc[m][ne] = __builtin_amdgcn_mfma_f32_16x16x32_bf16(
                        sA[m], vf, acc[m][ne], 0, 0, 0);
            }
        }
    }

    // ---- inter: Qd @ KV^T (bf16 states, direct B-frag reads) ----
    const u16* kvpb = kvstatesb + (size_t)(c * NH + h) * (HD * HD);
    const float dR0 = expf(-slope * (float)(i0 + lc + 1));
    const float dR1 = expf(-slope * (float)(i0 + 16 + lc + 1));
#pragma unroll
    for (int kk = 0; kk < 4; ++kk) {
        bf16x8 qd[2];
#pragma unroll
        for (int m = 0; m < 2; ++m) {
            const float dR = m ? dR1 : dR0;
            union { bf16x8 v; u32 u[4]; } qq;
            const u16* qe = (const u16*)&qa[m][kk];
#pragma unroll
            for (int x = 0; x < 4; ++x)
                qq.u[x] = pack2(b2f(qe[2 * x]) * dR, b2f(qe[2 * x + 1]) * dR);
            qd[m] = qq.v;
        }
#pragma unroll
        for (int ne = 0; ne < 8; ++ne) {
            bf16x8 kv = *(const bf16x8*)(kvpb + (size_t)(ne * 16 + lc) * HD + kk * 32 + lg * 8);
#pragma unroll
            for (int m = 0; m < 2; ++m)
                acc[m][ne] = __builtin_amdgcn_mfma_f32_16x16x32_bf16(
                    qd[m], kv, acc[m][ne], 0, 0, 0);
        }
    }

    // ---- store to q-slot ----
    u16* ob = qkvb + (size_t)(c * BLKC) * QKV_STRIDE + h * HD;
#pragma unroll
    for (int m = 0; m < 2; ++m)
#pragma unroll
        for (int ne = 0; ne < 8; ++ne)
#pragma unroll
            for (int r = 0; r < 4; ++r)
                ob[(size_t)(i0 + m * 16 + lg * 4 + r) * QKV_STRIDE + ne * 16 + lc] =
                    f2b(acc[m][ne][r]);
}

// ---------------------------------------------------------------------------
// Group RMSNorm * g_norm_w * sigmoid(g): q-slot x k-slot -> v-slot.
// ---------------------------------------------------------------------------
__global__ __launch_bounds__(256) void gate_kernel(u16* __restrict__ qkvb,
                                                   const u16* __restrict__ gnw) {
    const int b = blockIdx.x;
    const int s = b >> 3, grp = b & 7;
    const int t = threadIdx.x;
    const int j = (grp << 8) + t;
    const size_t base = (size_t)s * QKV_STRIDE;
    const float x = b2f(qkvb[base + j]);
    __shared__ float red[256];
    red[t] = x * x;
    __syncthreads();
    for (int off = 128; off > 0; off >>= 1) {
        if (t < off) red[t] += red[t + off];
        __syncthreads();
    }
    const float rstd = rsqrtf(red[0] * (1.f / 256.f) + EPSV);
    const float gv = b2f(qkvb[base + HID + j]);
    const float yv = x * rstd * b2f(gnw[j]) * (1.f / (1.f + expf(-gv)));
    qkvb[base + 2 * HID + j] = f2b(yv);
}

// ---------------------------------------------------------------------------
extern "C" void kernel_launch(void* const* d_in, const int* in_sizes, int n_in,
                              void* d_out, int out_size, void* d_ws, size_t ws_size,
                              hipStream_t stream) {
    const int* pos = (const int*)d_in[1];
    float* out = (float*)d_out;   // reference output dtype: float32
    char* ws = (char*)d_ws;

    // ---- canonical bf16 input area -------------------------------------
    u16*  c_hs    = (u16*)(ws + 256);                 // 16777216 el
    u16*  c_qkvw  = c_hs   + 16777216;                // 12582912 el
    u16*  c_qkvb  = c_qkvw + 12582912;                // 6144
    u16*  c_qn    = c_qkvb + 6144;                    // 128
    u16*  c_kn    = c_qn   + 128;                     // 128
    u16*  c_gw    = c_kn   + 128;                     // 4194304
    u16*  c_gnw   = c_gw   + 4194304;                 // 2048
    u16*  c_dw    = c_gnw  + 2048;                    // 4194304
    const size_t canon_end = 256 + (size_t)2 * (16777216 + 12582912 + 6144 + 128 + 128 + 4194304 + 2048 + 4194304);
    const size_t work_off = (canon_end + 255) & ~(size_t)255;

    // ---- pick super-chunk size to fit ws -------------------------------
    const size_t MB = 1048576;
    int SCR;
    if      (ws_size >= work_off + (size_t)2048 * QKV_STRIDE * 2 + 13 * MB) SCR = 2048;
    else if (ws_size >= work_off + (size_t)512  * QKV_STRIDE * 2 + 4 * MB)  SCR = 512;
    else                                                                     SCR = 256;
    const int NCS = SCR / BLKC;
    const int NSC = S_LEN / SCR;

    u16*   qkvb    = (u16*)(ws + work_off);
    float* states  = (float*)(ws + work_off + (size_t)SCR * QKV_STRIDE * 2);
    float* carry   = states + (size_t)NCS * NH * HD * HD;
    u16*   statesb = (u16*)(carry + (size_t)NH * HD * HD);

    const dim3 B256(256);

    // 0) canonize all fp32 float inputs to bf16
    canonize_kernel<<<dim3(16777216 / 1024), B256, 0, stream>>>((const float*)d_in[0], c_hs,   16777216);
    canonize_kernel<<<dim3(12582912 / 1024), B256, 0, stream>>>((const float*)d_in[2], c_qkvw, 12582912);
    canonize_kernel<<<dim3(6),               B256, 0, stream>>>((const float*)d_in[3], c_qkvb, 6144);
    canonize_kernel<<<dim3(1),               B256, 0, stream>>>((const float*)d_in[4], c_qn,   128);
    canonize_kernel<<<dim3(1),               B256, 0, stream>>>((const float*)d_in[5], c_kn,   128);
    canonize_kernel<<<dim3(4194304 / 1024),  B256, 0, stream>>>((const float*)d_in[6], c_gw,   4194304);
    canonize_kernel<<<dim3(2),               B256, 0, stream>>>((const float*)d_in[7], c_gnw,  2048);
    canonize_kernel<<<dim3(4194304 / 1024),  B256, 0, stream>>>((const float*)d_in[8], c_dw,   4194304);

    hipMemsetAsync(carry, 0, (size_t)NH * HD * HD * sizeof(float), stream);

    for (int sc = 0; sc < NSC; ++sc) {
        const int row0 = sc * SCR;
        const u16* hsb = c_hs + (size_t)row0 * HID;
        gemm_mfma<0><<<dim3(QKV_STRIDE / 128, SCR / 128), B256, 0, stream>>>(
            hsb, c_qkvw, c_qkvb, qkvb, HID, HID, HID, QKV_STRIDE);
        normrope_kernel<<<dim3(SCR * NH), dim3(128), 0, stream>>>(
            qkvb, c_qn, c_kn, pos, row0);
        kv_contrib_kernel<<<dim3(NCS * NH), B256, 0, stream>>>(qkvb, states);
        kv_scan_kernel<<<dim3(NH * HD * HD / 256), B256, 0, stream>>>(states, statesb, carry, NCS);
        attn_mfma_kernel<<<dim3(NCS * NH * 2), B256, 0, stream>>>(qkvb, statesb);
        gemm_mfma<0><<<dim3(HID / 128, SCR / 128), B256, 0, stream>>>(
            hsb, c_gw, nullptr, qkvb + HID, HID, HID, HID, QKV_STRIDE);
        gate_kernel<<<dim3(SCR * 8), B256, 0, stream>>>(qkvb, c_gnw);
        gemm_mfma<1><<<dim3(HID / 128, SCR / 128), B256, 0, stream>>>(
            qkvb + 2 * HID, c_dw, nullptr, out + (size_t)row0 * HID,
            HID, QKV_STRIDE, HID, HID);
    }
}

// Round 4
// 1180.471 us; speedup vs baseline: 4.4054x; 1.0943x over previous
//
#include <hip/hip_runtime.h>

#define S_LEN 8192
#define HID   2048
#define NH    16
#define HD    128
#define BLKC  256
#define QKV_STRIDE 6144
#define EPSV  1e-5f
#define SCALEF 0.08838834764831845f

typedef unsigned short u16;
typedef unsigned int   u32;
typedef __attribute__((ext_vector_type(8))) short bf16x8;
typedef __attribute__((ext_vector_type(4))) float f32x4;

__device__ __forceinline__ float b2f(u16 u) {
    unsigned int x = ((unsigned int)u) << 16;
    return __uint_as_float(x);
}
__device__ __forceinline__ u16 f2b(float f) {
    unsigned int u = __float_as_uint(f);
    u += 0x7fff + ((u >> 16) & 1);   // round-to-nearest-even
    return (u16)(u >> 16);
}
__device__ __forceinline__ u32 pack2(float lo, float hi) {
    return (u32)f2b(lo) | ((u32)f2b(hi) << 16);
}
__device__ __forceinline__ float get_slope(int h) {
    return exp2f(-0.5f * (float)(h + 1)) * 1.00001f;
}

#define GLOAD_LDS16(g, l)                                              \
    __builtin_amdgcn_global_load_lds(                                  \
        (const __attribute__((address_space(1))) void*)(g),            \
        (__attribute__((address_space(3))) void*)(l), 16, 0, 0)

// ---------------------------------------------------------------------------
// Canonize one fp32 tensor to bf16.
// ---------------------------------------------------------------------------
__global__ __launch_bounds__(256) void canonize_kernel(const float* __restrict__ src,
                                                       u16* __restrict__ dst, int n) {
    const int i0 = (blockIdx.x * 256 + threadIdx.x) * 4;
    if (i0 >= n) return;
    const float4 f = *(const float4*)(src + i0);
    ushort4 o;
    o.x = f2b(f.x); o.y = f2b(f.y); o.z = f2b(f.z); o.w = f2b(f.w);
    *(ushort4*)(dst + i0) = o;
}

// ---------------------------------------------------------------------------
// MFMA GEMM: C[M][N] = A[M][K] @ B[N][K]^T (+bias). bf16 in, f32 accum.
// ---------------------------------------------------------------------------
template<int OUT_F32>
__global__ __launch_bounds__(256) void gemm_mfma(const u16* __restrict__ A,
                                                 const u16* __restrict__ B,
                                                 const u16* __restrict__ bias,
                                                 void* __restrict__ Cv,
                                                 int K, int lda, int ldb, int ldc) {
    __shared__ u16 As[128 * 32];
    __shared__ u16 Bs[128 * 32];
    const int t = threadIdx.x;
    const int w = t >> 6;
    const int l = t & 63;
    const int row0 = blockIdx.y << 7, col0 = blockIdx.x << 7;

    const int se   = (w << 9) + (l << 3);
    const int srow = se >> 5;
    const int scol = se & 31;
    const u16* Ap = A + (size_t)(row0 + srow) * lda + scol;
    const u16* Bp = B + (size_t)(col0 + srow) * ldb + scol;
    u16* AsP = As + se;
    u16* BsP = Bs + se;

    const int wr = (w >> 1) << 6;
    const int wc = (w & 1) << 6;
    const int fr = l & 15;
    const int fk = (l >> 4) << 3;

    f32x4 acc[4][4] = {};

    for (int k0 = 0; k0 < K; k0 += 32) {
        __syncthreads();
        GLOAD_LDS16(Ap + k0, AsP);
        GLOAD_LDS16(Ap + k0 + (size_t)64 * lda, AsP + 64 * 32);
        GLOAD_LDS16(Bp + k0, BsP);
        GLOAD_LDS16(Bp + k0 + (size_t)64 * ldb, BsP + 64 * 32);
        __syncthreads();

        bf16x8 a[4], b[4];
#pragma unroll
        for (int m = 0; m < 4; ++m)
            a[m] = *(const bf16x8*)&As[(wr + (m << 4) + fr) * 32 + fk];
#pragma unroll
        for (int n = 0; n < 4; ++n)
            b[n] = *(const bf16x8*)&Bs[(wc + (n << 4) + fr) * 32 + fk];
#pragma unroll
        for (int m = 0; m < 4; ++m)
#pragma unroll
            for (int n = 0; n < 4; ++n)
                acc[m][n] = __builtin_amdgcn_mfma_f32_16x16x32_bf16(
                    a[m], b[n], acc[m][n], 0, 0, 0);
    }

    const int crow = row0 + wr + ((l >> 4) << 2);
    const int ccol = col0 + wc + fr;
#pragma unroll
    for (int n = 0; n < 4; ++n) {
        const float bv = (bias != nullptr) ? b2f(bias[ccol + (n << 4)]) : 0.f;
#pragma unroll
        for (int m = 0; m < 4; ++m) {
#pragma unroll
            for (int r = 0; r < 4; ++r) {
                const float val = acc[m][n][r] + bv;
                const size_t off = (size_t)(crow + (m << 4) + r) * ldc + ccol + (n << 4);
                if (OUT_F32) ((float*)Cv)[off] = val;
                else         ((u16*)Cv)[off]   = f2b(val);
            }
        }
    }
}

// ---------------------------------------------------------------------------
// Wave-per-(s,h): RMSNorm(q,k) -> RoPE -> q*=SCALE. In place. No LDS.
// Lane l owns the RoPE pair (d=l, d=l+64).
// ---------------------------------------------------------------------------
__global__ __launch_bounds__(256) void normrope_kernel(u16* __restrict__ qkvb,
                                                       const u16* __restrict__ qw,
                                                       const u16* __restrict__ kw,
                                                       const int* __restrict__ pos,
                                                       int row0) {
    const int wid = (blockIdx.x << 2) + (threadIdx.x >> 6);
    const int s = wid >> 4, h = wid & 15;
    const int l = threadIdx.x & 63;
    u16* qp = qkvb + (size_t)s * QKV_STRIDE + h * HD;
    u16* kp = qp + HID;
    const float q0 = b2f(qp[l]), q1 = b2f(qp[l + 64]);
    const float k0 = b2f(kp[l]), k1 = b2f(kp[l + 64]);
    float sq = q0 * q0 + q1 * q1;
    float sk = k0 * k0 + k1 * k1;
#pragma unroll
    for (int off = 32; off > 0; off >>= 1) {
        sq += __shfl_xor(sq, off);
        sk += __shfl_xor(sk, off);
    }
    const float qr = rsqrtf(sq * (1.f / 128.f) + EPSV);
    const float kr = rsqrtf(sk * (1.f / 128.f) + EPSV);
    const float nq0 = q0 * qr * b2f(qw[l]), nq1 = q1 * qr * b2f(qw[l + 64]);
    const float nk0 = k0 * kr * b2f(kw[l]), nk1 = k1 * kr * b2f(kw[l + 64]);
    const int p = pos[row0 + s];
    const float invf = powf(600000.f, -(float)l * (1.f / 64.f));
    const float fr = (float)p * invf;
    const float cs = cosf(fr), sn = sinf(fr);
    qp[l]      = f2b((nq0 * cs - nq1 * sn) * SCALEF);
    qp[l + 64] = f2b((nq1 * cs + nq0 * sn) * SCALEF);
    kp[l]      = f2b(nk0 * cs - nk1 * sn);
    kp[l + 64] = f2b(nk1 * cs + nk0 * sn);
}

// ---------------------------------------------------------------------------
// Per (local chunk, head, e-half): contribT[e][d] = sum_j kd[j] k[j][d] v[j][e]
// (TRANSPOSED output: [e][d].) Block covers 64 e x 128 d -> 2x parallelism.
// ---------------------------------------------------------------------------
__global__ __launch_bounds__(256) void kv_contrib_kernel(const u16* __restrict__ qkvb,
                                                         float* __restrict__ contrib) {
    const int b = blockIdx.x;
    const int eh = b & 1;
    const int h = (b >> 1) & 15;
    const int c = b >> 5;
    const float slope = get_slope(h);
    const u16* kb = qkvb + (size_t)c * BLKC * QKV_STRIDE + HID + h * HD;
    const u16* vb = kb + HID;
    const int t = threadIdx.x;
    const int tx = t & 15, ty = t >> 4;
    const int jj = t >> 5, dd = (t & 31) << 2;
    float acc[4][8] = {};
    __shared__ float kf[8][128], vf[8][128];
    for (int j0 = 0; j0 < BLKC; j0 += 8) {
        const float kd = expf(-slope * (float)(BLKC - 1 - (j0 + jj)));
        ushort4 k4 = *(const ushort4*)(kb + (size_t)(j0 + jj) * QKV_STRIDE + dd);
        ushort4 v4 = *(const ushort4*)(vb + (size_t)(j0 + jj) * QKV_STRIDE + dd);
        kf[jj][dd + 0] = b2f(k4.x) * kd; kf[jj][dd + 1] = b2f(k4.y) * kd;
        kf[jj][dd + 2] = b2f(k4.z) * kd; kf[jj][dd + 3] = b2f(k4.w) * kd;
        vf[jj][dd + 0] = b2f(v4.x); vf[jj][dd + 1] = b2f(v4.y);
        vf[jj][dd + 2] = b2f(v4.z); vf[jj][dd + 3] = b2f(v4.w);
        __syncthreads();
#pragma unroll
        for (int j = 0; j < 8; ++j) {
            float4 e0 = *(const float4*)&vf[j][(eh << 6) + (ty << 2)];
            float4 d0 = *(const float4*)&kf[j][tx << 3];
            float4 d1 = *(const float4*)&kf[j][(tx << 3) + 4];
            float er[4] = {e0.x, e0.y, e0.z, e0.w};
            float dr[8] = {d0.x, d0.y, d0.z, d0.w, d1.x, d1.y, d1.z, d1.w};
#pragma unroll
            for (int u = 0; u < 4; ++u)
#pragma unroll
                for (int v = 0; v < 8; ++v) acc[u][v] += er[u] * dr[v];
        }
        __syncthreads();
    }
    float* cb = contrib + ((size_t)(c * NH + h) * HD + (eh << 6) + (ty << 2)) * HD + (tx << 3);
#pragma unroll
    for (int u = 0; u < 4; ++u) {
        *(float4*)(cb + (size_t)u * HD)     = make_float4(acc[u][0], acc[u][1], acc[u][2], acc[u][3]);
        *(float4*)(cb + (size_t)u * HD + 4) = make_float4(acc[u][4], acc[u][5], acc[u][6], acc[u][7]);
    }
}

// ---------------------------------------------------------------------------
// Scan with carry across super-chunks. Reads f32 contribs; emits the
// state-before-chunk-c as BF16 into bufb (attn consumes bf16 directly).
// ---------------------------------------------------------------------------
__global__ __launch_bounds__(256) void kv_scan_kernel(const float* __restrict__ buf,
                                                      u16* __restrict__ bufb,
                                                      float* __restrict__ carry,
                                                      int ncs) {
    const int tid = blockIdx.x * 256 + threadIdx.x;   // < NH*HD*HD = 262144
    const int h = tid >> 14;
    const float bd = expf(-get_slope(h) * (float)BLKC);
    float prev = carry[tid];
    for (int c = 0; c < ncs; ++c) {
        const size_t off = (size_t)c * (NH * HD * HD) + tid;
        const float cur = buf[off];
        bufb[off] = f2b(prev);
        prev = bd * prev + cur;
    }
    carry[tid] = prev;
}

// ---------------------------------------------------------------------------
// MFMA attention. Block = (chunk, head, row-half). 4 waves x 32 q-rows.
//   intra: S = QK^T (MFMA), decay+mask in-reg, S->bf16 pack into a per-wave
//          swizzled bounce buffer, then S@V (MFMA) with V^T staged in LDS
//          under a permuted k-order sigma(p): j = (p&1)*16 + (p>>1).
//   inter: (Q * qdecay) @ KV^T (MFMA) from bf16 transposed states.
// ---------------------------------------------------------------------------
__global__ __launch_bounds__(256) void attn_mfma_kernel(u16* __restrict__ qkvb,
                                                        const u16* __restrict__ kvstatesb) {
    const int b  = blockIdx.x;
    const int hb = b & 1;
    const int h  = (b >> 1) & 15;
    const int c  = b >> 5;
    const float slope = get_slope(h);
    const int t  = threadIdx.x;
    const int w  = t >> 6, l = t & 63;
    const int lg = l >> 4, lc = l & 15;
    const int giw = hb * 4 + w;          // global i-tile 0..7
    const int i0  = giw << 5;            // row base within chunk

    __shared__ u16 Ks[32 * 128];         // swizzled K tile: slot' = slot ^ (j&7)
    __shared__ u16 Vt[128 * 40];         // Vt[e][p] sigma-permuted, stride 40
    __shared__ u16 Sb[4 * 1024];         // per-wave 32x16-u32 bounce (2KB each)

    // ---- Q fragments (A-layout): rows i0+m*16+lc, k-slice kk*32+lg*8 ----
    const u16* qbase = qkvb + (size_t)(c * BLKC) * QKV_STRIDE + h * HD;
    bf16x8 qa[2][4];
#pragma unroll
    for (int m = 0; m < 2; ++m)
#pragma unroll
        for (int kk = 0; kk < 4; ++kk)
            qa[m][kk] = *(const bf16x8*)(qbase +
                (size_t)(i0 + m * 16 + lc) * QKV_STRIDE + kk * 32 + lg * 8);

    f32x4 acc[2][8] = {};

    const u16* kbase = qkvb + (size_t)(c * BLKC) * QKV_STRIDE + HID + h * HD;
    const u16* vbase = kbase + HID;
    const int jtmax = hb * 4 + 4;
    const int ve  = t & 127;             // e-row for V gather
    const int vph = t >> 7;              // phase: p0 = 0/8
    u16* SbW = Sb + (w << 10);

    for (int jt = 0; jt < jtmax; ++jt) {
        __syncthreads();
        // -- stage K: linear LDS dest, pre-swizzled global source --
#pragma unroll
        for (int u = 0; u < 2; ++u) {
            const int idx = t + (u << 8);
            const int j = idx >> 4, s = idx & 15;
            const int sp = s ^ (j & 7);
            GLOAD_LDS16(kbase + (size_t)(jt * 32 + j) * QKV_STRIDE + sp * 8,
                        Ks + idx * 8);
        }
        // -- gather V^T (coalesced 2B global loads, b128 LDS writes) --
        union { int4 q; u16 e[8]; } vv[2];
#pragma unroll
        for (int u = 0; u < 2; ++u) {
            const int p0 = vph * 8 + u * 16;
#pragma unroll
            for (int x = 0; x < 8; ++x) {
                const int p = p0 + x;
                const int j = ((p & 1) << 4) | (p >> 1);
                vv[u].e[x] = vbase[(size_t)(jt * 32 + j) * QKV_STRIDE + ve];
            }
        }
#pragma unroll
        for (int u = 0; u < 2; ++u) {
            const int p0 = vph * 8 + u * 16;
            *(int4*)&Vt[ve * 40 + p0] = vv[u].q;
        }
        __syncthreads();

        if (jt <= giw) {
            // -- QK^T --
            f32x4 sacc[2][2] = {};
#pragma unroll
            for (int kk = 0; kk < 4; ++kk) {
#pragma unroll
                for (int nj = 0; nj < 2; ++nj) {
                    const int j = nj * 16 + lc;
                    const int sp = (kk * 4 + lg) ^ (j & 7);
                    bf16x8 kf = *(const bf16x8*)&Ks[j * 128 + sp * 8];
#pragma unroll
                    for (int m = 0; m < 2; ++m)
                        sacc[m][nj] = __builtin_amdgcn_mfma_f32_16x16x32_bf16(
                            qa[m][kk], kf, sacc[m][nj], 0, 0, 0);
                }
            }
            // -- decay + mask + pack into per-wave swizzled bounce --
            const int di0 = i0 - jt * 32;
            const float cj0 = expf(slope * (float)lc);
            const float cj1 = expf(slope * (float)(16 + lc));
            const bool diag = (jt == giw);
#pragma unroll
            for (int m = 0; m < 2; ++m) {
#pragma unroll
                for (int r = 0; r < 4; ++r) {
                    const int irel = m * 16 + lg * 4 + r;     // i - i0
                    const float rex = expf(-slope * (float)(di0 + irel));
                    float v0 = sacc[m][0][r] * rex * cj0;
                    float v1 = sacc[m][1][r] * rex * cj1;
                    if (diag) {
                        if (irel < lc)      v0 = 0.f;
                        if (irel < 16 + lc) v1 = 0.f;
                    }
                    const u32 pk = pack2(v0, v1);
                    const int iL = irel;
                    const int rp = iL ^ ((iL >> 2) & 1);
                    *(u32*)&SbW[rp * 32 + ((lc << 1) ^ (((iL >> 2) & 3) << 3))] = pk;
                }
            }
            // -- read S as A-frags, SV MFMA --
            bf16x8 sA[2];
#pragma unroll
            for (int m = 0; m < 2; ++m) {
                const int iL = m * 16 + lc;
                const int rp = iL ^ ((iL >> 2) & 1);
                sA[m] = *(const bf16x8*)&SbW[rp * 32 + ((lg << 3) ^ (((iL >> 2) & 3) << 3))];
            }
#pragma unroll
            for (int ne = 0; ne < 8; ++ne) {
                bf16x8 vf = *(const bf16x8*)&Vt[(ne * 16 + lc) * 40 + lg * 8];
#pragma unroll
                for (int m = 0; m < 2; ++m)
                    acc[m][ne] = __builtin_amdgcn_mfma_f32_16x16x32_bf16(
                        sA[m], vf, acc[m][ne], 0, 0, 0);
            }
        }
    }

    // ---- inter: Qd @ KV^T (bf16 states, direct B-frag reads) ----
    const u16* kvpb = kvstatesb + (size_t)(c * NH + h) * (HD * HD);
    const float dR0 = expf(-slope * (float)(i0 + lc + 1));
    const float dR1 = expf(-slope * (float)(i0 + 16 + lc + 1));
#pragma unroll
    for (int kk = 0; kk < 4; ++kk) {
        bf16x8 qd[2];
#pragma unroll
        for (int m = 0; m < 2; ++m) {
            const float dR = m ? dR1 : dR0;
            union { bf16x8 v; u32 u[4]; } qq;
            const u16* qe = (const u16*)&qa[m][kk];
#pragma unroll
            for (int x = 0; x < 4; ++x)
                qq.u[x] = pack2(b2f(qe[2 * x]) * dR, b2f(qe[2 * x + 1]) * dR);
            qd[m] = qq.v;
        }
#pragma unroll
        for (int ne = 0; ne < 8; ++ne) {
            bf16x8 kv = *(const bf16x8*)(kvpb + (size_t)(ne * 16 + lc) * HD + kk * 32 + lg * 8);
#pragma unroll
            for (int m = 0; m < 2; ++m)
                acc[m][ne] = __builtin_amdgcn_mfma_f32_16x16x32_bf16(
                    qd[m], kv, acc[m][ne], 0, 0, 0);
        }
    }

    // ---- store to q-slot ----
    u16* ob = qkvb + (size_t)(c * BLKC) * QKV_STRIDE + h * HD;
#pragma unroll
    for (int m = 0; m < 2; ++m)
#pragma unroll
        for (int ne = 0; ne < 8; ++ne)
#pragma unroll
            for (int r = 0; r < 4; ++r)
                ob[(size_t)(i0 + m * 16 + lg * 4 + r) * QKV_STRIDE + ne * 16 + lc] =
                    f2b(acc[m][ne][r]);
}

// ---------------------------------------------------------------------------
// Group RMSNorm * g_norm_w * sigmoid(g): one block per row, 8 elems/thread.
// Group = 256 elems = 32 contiguous lanes; shuffle reduce within 32.
// ---------------------------------------------------------------------------
__global__ __launch_bounds__(256) void gate_kernel(u16* __restrict__ qkvb,
                                                   const u16* __restrict__ gnw) {
    const int s = blockIdx.x;
    const int t = threadIdx.x;
    const int j = t << 3;
    const size_t base = (size_t)s * QKV_STRIDE;
    union { int4 v; u16 e[8]; } xr, gr, wv;
    xr.v = *(const int4*)(qkvb + base + j);
    gr.v = *(const int4*)(qkvb + base + HID + j);
    wv.v = *(const int4*)(gnw + j);
    float x[8];
    float ss = 0.f;
#pragma unroll
    for (int i = 0; i < 8; ++i) { x[i] = b2f(xr.e[i]); ss += x[i] * x[i]; }
#pragma unroll
    for (int off = 16; off > 0; off >>= 1) ss += __shfl_xor(ss, off, 32);
    const float rstd = rsqrtf(ss * (1.f / 256.f) + EPSV);
    union { int4 v; u16 e[8]; } o;
#pragma unroll
    for (int i = 0; i < 8; ++i) {
        const float yv = x[i] * rstd * b2f(wv.e[i]) *
                         (1.f / (1.f + expf(-b2f(gr.e[i]))));
        o.e[i] = f2b(yv);
    }
    *(int4*)(qkvb + base + 2 * HID + j) = o.v;
}

// ---------------------------------------------------------------------------
extern "C" void kernel_launch(void* const* d_in, const int* in_sizes, int n_in,
                              void* d_out, int out_size, void* d_ws, size_t ws_size,
                              hipStream_t stream) {
    const int* pos = (const int*)d_in[1];
    float* out = (float*)d_out;   // reference output dtype: float32
    char* ws = (char*)d_ws;

    // ---- canonical bf16 input area -------------------------------------
    u16*  c_hs    = (u16*)(ws + 256);                 // 16777216 el
    u16*  c_qkvw  = c_hs   + 16777216;                // 12582912 el
    u16*  c_qkvb  = c_qkvw + 12582912;                // 6144
    u16*  c_qn    = c_qkvb + 6144;                    // 128
    u16*  c_kn    = c_qn   + 128;                     // 128
    u16*  c_gw    = c_kn   + 128;                     // 4194304
    u16*  c_gnw   = c_gw   + 4194304;                 // 2048
    u16*  c_dw    = c_gnw  + 2048;                    // 4194304
    const size_t canon_end = 256 + (size_t)2 * (16777216 + 12582912 + 6144 + 128 + 128 + 4194304 + 2048 + 4194304);
    const size_t work_off = (canon_end + 255) & ~(size_t)255;

    // ---- pick super-chunk size to fit ws -------------------------------
    const size_t MB = 1048576;
    int SCR;
    if      (ws_size >= work_off + (size_t)2048 * QKV_STRIDE * 2 + 13 * MB) SCR = 2048;
    else if (ws_size >= work_off + (size_t)512  * QKV_STRIDE * 2 + 4 * MB)  SCR = 512;
    else                                                                     SCR = 256;
    const int NCS = SCR / BLKC;
    const int NSC = S_LEN / SCR;

    u16*   qkvb    = (u16*)(ws + work_off);
    float* states  = (float*)(ws + work_off + (size_t)SCR * QKV_STRIDE * 2);
    float* carry   = states + (size_t)NCS * NH * HD * HD;
    u16*   statesb = (u16*)(carry + (size_t)NH * HD * HD);

    const dim3 B256(256);

    // 0) canonize all fp32 float inputs to bf16
    canonize_kernel<<<dim3(16777216 / 1024), B256, 0, stream>>>((const float*)d_in[0], c_hs,   16777216);
    canonize_kernel<<<dim3(12582912 / 1024), B256, 0, stream>>>((const float*)d_in[2], c_qkvw, 12582912);
    canonize_kernel<<<dim3(6),               B256, 0, stream>>>((const float*)d_in[3], c_qkvb, 6144);
    canonize_kernel<<<dim3(1),               B256, 0, stream>>>((const float*)d_in[4], c_qn,   128);
    canonize_kernel<<<dim3(1),               B256, 0, stream>>>((const float*)d_in[5], c_kn,   128);
    canonize_kernel<<<dim3(4194304 / 1024),  B256, 0, stream>>>((const float*)d_in[6], c_gw,   4194304);
    canonize_kernel<<<dim3(2),               B256, 0, stream>>>((const float*)d_in[7], c_gnw,  2048);
    canonize_kernel<<<dim3(4194304 / 1024),  B256, 0, stream>>>((const float*)d_in[8], c_dw,   4194304);

    hipMemsetAsync(carry, 0, (size_t)NH * HD * HD * sizeof(float), stream);

    for (int sc = 0; sc < NSC; ++sc) {
        const int row0 = sc * SCR;
        const u16* hsb = c_hs + (size_t)row0 * HID;
        gemm_mfma<0><<<dim3(QKV_STRIDE / 128, SCR / 128), B256, 0, stream>>>(
            hsb, c_qkvw, c_qkvb, qkvb, HID, HID, HID, QKV_STRIDE);
        normrope_kernel<<<dim3(SCR * NH / 4), B256, 0, stream>>>(
            qkvb, c_qn, c_kn, pos, row0);
        kv_contrib_kernel<<<dim3(NCS * NH * 2), B256, 0, stream>>>(qkvb, states);
        kv_scan_kernel<<<dim3(NH * HD * HD / 256), B256, 0, stream>>>(states, statesb, carry, NCS);
        attn_mfma_kernel<<<dim3(NCS * NH * 2), B256, 0, stream>>>(qkvb, statesb);
        gemm_mfma<0><<<dim3(HID / 128, SCR / 128), B256, 0, stream>>>(
            hsb, c_gw, nullptr, qkvb + HID, HID, HID, HID, QKV_STRIDE);
        gate_kernel<<<dim3(SCR), B256, 0, stream>>>(qkvb, c_gnw);
        gemm_mfma<1><<<dim3(HID / 128, SCR / 128), B256, 0, stream>>>(
            qkvb + 2 * HID, c_dw, nullptr, out + (size_t)row0 * HID,
            HID, QKV_STRIDE, HID, HID);
    }
}

// Round 5
// 1019.812 us; speedup vs baseline: 5.0994x; 1.1575x over previous
//
#include <hip/hip_runtime.h>

#define S_LEN 8192
#define HID   2048
#define NH    16
#define HD    128
#define BLKC  256
#define QKV_STRIDE 6144
#define EPSV  1e-5f
#define SCALEF 0.08838834764831845f

typedef unsigned short u16;
typedef unsigned int   u32;
typedef __attribute__((ext_vector_type(8))) short bf16x8;
typedef __attribute__((ext_vector_type(4))) float f32x4;

__device__ __forceinline__ float b2f(u16 u) {
    unsigned int x = ((unsigned int)u) << 16;
    return __uint_as_float(x);
}
__device__ __forceinline__ u16 f2b(float f) {
    unsigned int u = __float_as_uint(f);
    u += 0x7fff + ((u >> 16) & 1);   // round-to-nearest-even
    return (u16)(u >> 16);
}
__device__ __forceinline__ u32 pack2(float lo, float hi) {
    return (u32)f2b(lo) | ((u32)f2b(hi) << 16);
}
__device__ __forceinline__ float get_slope(int h) {
    return exp2f(-0.5f * (float)(h + 1)) * 1.00001f;
}

#define GLOAD_LDS16(g, l)                                              \
    __builtin_amdgcn_global_load_lds(                                  \
        (const __attribute__((address_space(1))) void*)(g),            \
        (__attribute__((address_space(3))) void*)(l), 16, 0, 0)

// raw barrier with compiler memory fence (no vmcnt drain!)
#define BARF() do { asm volatile("" ::: "memory");                     \
                    __builtin_amdgcn_s_barrier();                      \
                    asm volatile("" ::: "memory"); } while (0)
#define VMW(n) asm volatile("s_waitcnt vmcnt(" #n ")" ::: "memory")

// ---------------------------------------------------------------------------
// Canonize one fp32 tensor to bf16.
// ---------------------------------------------------------------------------
__global__ __launch_bounds__(256) void canonize_kernel(const float* __restrict__ src,
                                                       u16* __restrict__ dst, int n) {
    const int i0 = (blockIdx.x * 256 + threadIdx.x) * 4;
    if (i0 >= n) return;
    const float4 f = *(const float4*)(src + i0);
    ushort4 o;
    o.x = f2b(f.x); o.y = f2b(f.y); o.z = f2b(f.z); o.w = f2b(f.w);
    *(ushort4*)(dst + i0) = o;
}

// ---------------------------------------------------------------------------
// 8-phase 256x256 fused GEMM: C = A[M][2048] @ concat(qkvw,gw)[8192][2048]^T.
// blockIdx.x < 24 -> qkv cols (bias, out Cq ld 6144); else g cols (out Cg).
// K=2048 fixed. 512 thr / 8 waves (2Mx4N), per-wave 128x64. LDS 128 KiB:
// A[2 dbuf][2 khalf][256][32] + B same. Swizzle slot^=row&3 both sides.
// Counted vmcnt(8) (never 0 in main loop), raw s_barrier, setprio MFMA.
// ---------------------------------------------------------------------------
template<int D, int KH, int MH>
__device__ __forceinline__ void rd_a(const u16* lds, int aoff0, bf16x8 af[4]) {
#pragma unroll
    for (int mm = 0; mm < 4; ++mm)
        af[mm] = *(const bf16x8*)&lds[D * 16384 + KH * 8192 + (MH * 4 + mm) * 512 + aoff0];
}
template<int D, int KH>
__device__ __forceinline__ void rd_b(const u16* lds, int boff0, bf16x8 bf[4]) {
#pragma unroll
    for (int nn = 0; nn < 4; ++nn)
        bf[nn] = *(const bf16x8*)&lds[32768 + D * 16384 + KH * 8192 + nn * 512 + boff0];
}
template<int MH>
__device__ __forceinline__ void mf(const bf16x8 af[4], const bf16x8 bf[4],
                                   f32x4 (&acc)[8][4]) {
    __builtin_amdgcn_s_setprio(1);
#pragma unroll
    for (int mm = 0; mm < 4; ++mm)
#pragma unroll
        for (int nn = 0; nn < 4; ++nn)
            acc[MH * 4 + mm][nn] = __builtin_amdgcn_mfma_f32_16x16x32_bf16(
                af[mm], bf[nn], acc[MH * 4 + mm][nn], 0, 0, 0);
    __builtin_amdgcn_s_setprio(0);
}

__global__ __launch_bounds__(512, 2) void gemm256_fused(const u16* __restrict__ A,
                                                        const u16* __restrict__ qkvw,
                                                        const u16* __restrict__ gw,
                                                        const u16* __restrict__ bias,
                                                        u16* __restrict__ Cq,
                                                        u16* __restrict__ Cg) {
    __shared__ u16 lds[65536];          // 128 KiB: A at 0, B at 32768
    const int tid = threadIdx.x;
    const int w = tid >> 6, l = tid & 63;
    const int row0 = blockIdx.y << 8;
    const int col0 = blockIdx.x << 8;
    const bool isq = (blockIdx.x < 24);
    const u16* Bsel = isq ? qkvw : gw;
    const int bcol0 = isq ? col0 : (col0 - 6144);

    // staging addresses: thread t stages row u*128 + t/4, slot t&3 (swizzled src)
    const int scol = (((tid & 3) ^ ((tid >> 2) & 3)) << 3);
    const u16* aSrc = A    + (size_t)(row0  + (tid >> 2)) * 2048 + scol;
    const u16* bSrc = Bsel + (size_t)(bcol0 + (tid >> 2)) * 2048 + scol;

#define STAGE_A(d, kh, tk) do {                                                        \
    GLOAD_LDS16(aSrc + (size_t)(tk) * 64 + (kh) * 32,                                  \
                lds + (d) * 16384 + (kh) * 8192 + tid * 8);                            \
    GLOAD_LDS16(aSrc + (size_t)128 * 2048 + (size_t)(tk) * 64 + (kh) * 32,             \
                lds + (d) * 16384 + (kh) * 8192 + 4096 + tid * 8); } while (0)
#define STAGE_B(d, kh, tk) do {                                                        \
    GLOAD_LDS16(bSrc + (size_t)(tk) * 64 + (kh) * 32,                                  \
                lds + 32768 + (d) * 16384 + (kh) * 8192 + tid * 8);                    \
    GLOAD_LDS16(bSrc + (size_t)128 * 2048 + (size_t)(tk) * 64 + (kh) * 32,             \
                lds + 32768 + (d) * 16384 + (kh) * 8192 + 4096 + tid * 8); } while (0)

    // fragment read offsets (swizzle slot ^ (row&3); row&3 == l&3)
    const int wr = (w >> 2) << 7;       // 0 / 128
    const int wc = (w & 3) << 6;        // 0 / 64 / 128 / 192
    const int fslot = (((l >> 4) ^ (l & 3)) << 3);
    const int aoff0 = (wr + (l & 15)) * 32 + fslot;
    const int boff0 = (wc + (l & 15)) * 32 + fslot;

    f32x4 acc[8][4] = {};
    bf16x8 af[4], bf[4];

    // prologue: kh0(0), kh1(0), kh0(1)  (6 stages = 12 loads)
    STAGE_A(0, 0, 0); STAGE_B(0, 0, 0);
    STAGE_A(0, 1, 0); STAGE_B(0, 1, 0);
    STAGE_A(1, 0, 1); STAGE_B(1, 0, 1);

    // main loop: tiles 0..29 (T=32), unrolled x2 for static buffer index
    for (int tk = 0; tk < 30; tk += 2) {
        // ---- tile tk (d=0) ----
        VMW(8); BARF();
        rd_a<0, 0, 0>(lds, aoff0, af); rd_b<0, 0>(lds, boff0, bf);
        STAGE_A(1, 1, tk + 1);
        BARF(); mf<0>(af, bf, acc);
        BARF();
        rd_a<0, 0, 1>(lds, aoff0, af);
        STAGE_B(1, 1, tk + 1);
        BARF(); mf<1>(af, bf, acc);
        VMW(8); BARF();
        rd_a<0, 1, 0>(lds, aoff0, af); rd_b<0, 1>(lds, boff0, bf);
        STAGE_A(0, 0, tk + 2);
        BARF(); mf<0>(af, bf, acc);
        BARF();
        rd_a<0, 1, 1>(lds, aoff0, af);
        STAGE_B(0, 0, tk + 2);
        BARF(); mf<1>(af, bf, acc);
        // ---- tile tk+1 (d=1) ----
        VMW(8); BARF();
        rd_a<1, 0, 0>(lds, aoff0, af); rd_b<1, 0>(lds, boff0, bf);
        STAGE_A(0, 1, tk + 2);
        BARF(); mf<0>(af, bf, acc);
        BARF();
        rd_a<1, 0, 1>(lds, aoff0, af);
        STAGE_B(0, 1, tk + 2);
        BARF(); mf<1>(af, bf, acc);
        VMW(8); BARF();
        rd_a<1, 1, 0>(lds, aoff0, af); rd_b<1, 1>(lds, boff0, bf);
        STAGE_A(1, 0, tk + 3);
        BARF(); mf<0>(af, bf, acc);
        BARF();
        rd_a<1, 1, 1>(lds, aoff0, af);
        STAGE_B(1, 0, tk + 3);
        BARF(); mf<1>(af, bf, acc);
    }
    // ---- tile 30 (d=0): stage only kh1(31) ----
    VMW(8); BARF();
    rd_a<0, 0, 0>(lds, aoff0, af); rd_b<0, 0>(lds, boff0, bf);
    STAGE_A(1, 1, 31);
    BARF(); mf<0>(af, bf, acc);
    BARF();
    rd_a<0, 0, 1>(lds, aoff0, af);
    STAGE_B(1, 1, 31);
    BARF(); mf<1>(af, bf, acc);
    VMW(8); BARF();
    rd_a<0, 1, 0>(lds, aoff0, af); rd_b<0, 1>(lds, boff0, bf);
    BARF(); mf<0>(af, bf, acc);
    BARF();
    rd_a<0, 1, 1>(lds, aoff0, af);
    BARF(); mf<1>(af, bf, acc);
    // ---- tile 31 (d=1): no stages ----
    VMW(4); BARF();
    rd_a<1, 0, 0>(lds, aoff0, af); rd_b<1, 0>(lds, boff0, bf);
    BARF(); mf<0>(af, bf, acc);
    BARF();
    rd_a<1, 0, 1>(lds, aoff0, af);
    BARF(); mf<1>(af, bf, acc);
    VMW(0); BARF();
    rd_a<1, 1, 0>(lds, aoff0, af); rd_b<1, 1>(lds, boff0, bf);
    BARF(); mf<0>(af, bf, acc);
    BARF();
    rd_a<1, 1, 1>(lds, aoff0, af);
    BARF(); mf<1>(af, bf, acc);
#undef STAGE_A
#undef STAGE_B

    // ---- epilogue: C/D layout col=lane&15, row=(lane>>4)*4+reg ----
    u16* Cout = isq ? Cq : Cg;
    const int ldc = isq ? 6144 : 2048;
    const int ccb = (isq ? col0 : (col0 - 6144)) + wc + (l & 15);
    const int crb = row0 + wr + ((l >> 4) << 2);
#pragma unroll
    for (int nn = 0; nn < 4; ++nn) {
        const float bv = isq ? b2f(bias[col0 + wc + nn * 16 + (l & 15)]) : 0.f;
#pragma unroll
        for (int mm = 0; mm < 8; ++mm) {
#pragma unroll
            for (int r = 0; r < 4; ++r)
                Cout[(size_t)(crb + mm * 16 + r) * ldc + ccb + nn * 16] =
                    f2b(acc[mm][nn][r] + bv);
        }
    }
}

// ---------------------------------------------------------------------------
// MFMA GEMM (128x128, m97 structure): C = A @ B^T (+bias). Used for dense.
// ---------------------------------------------------------------------------
template<int OUT_F32>
__global__ __launch_bounds__(256) void gemm_mfma(const u16* __restrict__ A,
                                                 const u16* __restrict__ B,
                                                 const u16* __restrict__ bias,
                                                 void* __restrict__ Cv,
                                                 int K, int lda, int ldb, int ldc) {
    __shared__ u16 As[128 * 32];
    __shared__ u16 Bs[128 * 32];
    const int t = threadIdx.x;
    const int w = t >> 6;
    const int l = t & 63;
    const int row0 = blockIdx.y << 7, col0 = blockIdx.x << 7;

    const int se   = (w << 9) + (l << 3);
    const int srow = se >> 5;
    const int scol = se & 31;
    const u16* Ap = A + (size_t)(row0 + srow) * lda + scol;
    const u16* Bp = B + (size_t)(col0 + srow) * ldb + scol;
    u16* AsP = As + se;
    u16* BsP = Bs + se;

    const int wr = (w >> 1) << 6;
    const int wc = (w & 1) << 6;
    const int fr = l & 15;
    const int fk = (l >> 4) << 3;

    f32x4 acc[4][4] = {};

    for (int k0 = 0; k0 < K; k0 += 32) {
        __syncthreads();
        GLOAD_LDS16(Ap + k0, AsP);
        GLOAD_LDS16(Ap + k0 + (size_t)64 * lda, AsP + 64 * 32);
        GLOAD_LDS16(Bp + k0, BsP);
        GLOAD_LDS16(Bp + k0 + (size_t)64 * ldb, BsP + 64 * 32);
        __syncthreads();

        bf16x8 a[4], b[4];
#pragma unroll
        for (int m = 0; m < 4; ++m)
            a[m] = *(const bf16x8*)&As[(wr + (m << 4) + fr) * 32 + fk];
#pragma unroll
        for (int n = 0; n < 4; ++n)
            b[n] = *(const bf16x8*)&Bs[(wc + (n << 4) + fr) * 32 + fk];
#pragma unroll
        for (int m = 0; m < 4; ++m)
#pragma unroll
            for (int n = 0; n < 4; ++n)
                acc[m][n] = __builtin_amdgcn_mfma_f32_16x16x32_bf16(
                    a[m], b[n], acc[m][n], 0, 0, 0);
    }

    const int crow = row0 + wr + ((l >> 4) << 2);
    const int ccol = col0 + wc + fr;
#pragma unroll
    for (int n = 0; n < 4; ++n) {
        const float bv = (bias != nullptr) ? b2f(bias[ccol + (n << 4)]) : 0.f;
#pragma unroll
        for (int m = 0; m < 4; ++m) {
#pragma unroll
            for (int r = 0; r < 4; ++r) {
                const float val = acc[m][n][r] + bv;
                const size_t off = (size_t)(crow + (m << 4) + r) * ldc + ccol + (n << 4);
                if (OUT_F32) ((float*)Cv)[off] = val;
                else         ((u16*)Cv)[off]   = f2b(val);
            }
        }
    }
}

// ---------------------------------------------------------------------------
// Wave-per-(s,h): RMSNorm(q,k) -> RoPE -> q*=SCALE. In place. No LDS.
// ---------------------------------------------------------------------------
__global__ __launch_bounds__(256) void normrope_kernel(u16* __restrict__ qkvb,
                                                       const u16* __restrict__ qw,
                                                       const u16* __restrict__ kw,
                                                       const int* __restrict__ pos,
                                                       int row0) {
    const int wid = (blockIdx.x << 2) + (threadIdx.x >> 6);
    const int s = wid >> 4, h = wid & 15;
    const int l = threadIdx.x & 63;
    u16* qp = qkvb + (size_t)s * QKV_STRIDE + h * HD;
    u16* kp = qp + HID;
    const float q0 = b2f(qp[l]), q1 = b2f(qp[l + 64]);
    const float k0 = b2f(kp[l]), k1 = b2f(kp[l + 64]);
    float sq = q0 * q0 + q1 * q1;
    float sk = k0 * k0 + k1 * k1;
#pragma unroll
    for (int off = 32; off > 0; off >>= 1) {
        sq += __shfl_xor(sq, off);
        sk += __shfl_xor(sk, off);
    }
    const float qr = rsqrtf(sq * (1.f / 128.f) + EPSV);
    const float kr = rsqrtf(sk * (1.f / 128.f) + EPSV);
    const float nq0 = q0 * qr * b2f(qw[l]), nq1 = q1 * qr * b2f(qw[l + 64]);
    const float nk0 = k0 * kr * b2f(kw[l]), nk1 = k1 * kr * b2f(kw[l + 64]);
    const int p = pos[row0 + s];
    const float invf = powf(600000.f, -(float)l * (1.f / 64.f));
    const float fr = (float)p * invf;
    const float cs = cosf(fr), sn = sinf(fr);
    qp[l]      = f2b((nq0 * cs - nq1 * sn) * SCALEF);
    qp[l + 64] = f2b((nq1 * cs + nq0 * sn) * SCALEF);
    kp[l]      = f2b(nk0 * cs - nk1 * sn);
    kp[l + 64] = f2b(nk1 * cs + nk0 * sn);
}

// ---------------------------------------------------------------------------
// Per (local chunk, head, e-half): contribT[e][d] = sum_j kd[j] k[j][d] v[j][e]
// ---------------------------------------------------------------------------
__global__ __launch_bounds__(256) void kv_contrib_kernel(const u16* __restrict__ qkvb,
                                                         float* __restrict__ contrib) {
    const int b = blockIdx.x;
    const int eh = b & 1;
    const int h = (b >> 1) & 15;
    const int c = b >> 5;
    const float slope = get_slope(h);
    const u16* kb = qkvb + (size_t)c * BLKC * QKV_STRIDE + HID + h * HD;
    const u16* vb = kb + HID;
    const int t = threadIdx.x;
    const int tx = t & 15, ty = t >> 4;
    const int jj = t >> 5, dd = (t & 31) << 2;
    float acc[4][8] = {};
    __shared__ float kf[8][128], vf[8][128];
    for (int j0 = 0; j0 < BLKC; j0 += 8) {
        const float kd = expf(-slope * (float)(BLKC - 1 - (j0 + jj)));
        ushort4 k4 = *(const ushort4*)(kb + (size_t)(j0 + jj) * QKV_STRIDE + dd);
        ushort4 v4 = *(const ushort4*)(vb + (size_t)(j0 + jj) * QKV_STRIDE + dd);
        kf[jj][dd + 0] = b2f(k4.x) * kd; kf[jj][dd + 1] = b2f(k4.y) * kd;
        kf[jj][dd + 2] = b2f(k4.z) * kd; kf[jj][dd + 3] = b2f(k4.w) * kd;
        vf[jj][dd + 0] = b2f(v4.x); vf[jj][dd + 1] = b2f(v4.y);
        vf[jj][dd + 2] = b2f(v4.z); vf[jj][dd + 3] = b2f(v4.w);
        __syncthreads();
#pragma unroll
        for (int j = 0; j < 8; ++j) {
            float4 e0 = *(const float4*)&vf[j][(eh << 6) + (ty << 2)];
            float4 d0 = *(const float4*)&kf[j][tx << 3];
            float4 d1 = *(const float4*)&kf[j][(tx << 3) + 4];
            float er[4] = {e0.x, e0.y, e0.z, e0.w};
            float dr[8] = {d0.x, d0.y, d0.z, d0.w, d1.x, d1.y, d1.z, d1.w};
#pragma unroll
            for (int u = 0; u < 4; ++u)
#pragma unroll
                for (int v = 0; v < 8; ++v) acc[u][v] += er[u] * dr[v];
        }
        __syncthreads();
    }
    float* cb = contrib + ((size_t)(c * NH + h) * HD + (eh << 6) + (ty << 2)) * HD + (tx << 3);
#pragma unroll
    for (int u = 0; u < 4; ++u) {
        *(float4*)(cb + (size_t)u * HD)     = make_float4(acc[u][0], acc[u][1], acc[u][2], acc[u][3]);
        *(float4*)(cb + (size_t)u * HD + 4) = make_float4(acc[u][4], acc[u][5], acc[u][6], acc[u][7]);
    }
}

// ---------------------------------------------------------------------------
// Scan with carry across super-chunks; emits bf16 prefix states.
// ---------------------------------------------------------------------------
__global__ __launch_bounds__(256) void kv_scan_kernel(const float* __restrict__ buf,
                                                      u16* __restrict__ bufb,
                                                      float* __restrict__ carry,
                                                      int ncs) {
    const int tid = blockIdx.x * 256 + threadIdx.x;   // < NH*HD*HD = 262144
    const int h = tid >> 14;
    const float bd = expf(-get_slope(h) * (float)BLKC);
    float prev = carry[tid];
    for (int c = 0; c < ncs; ++c) {
        const size_t off = (size_t)c * (NH * HD * HD) + tid;
        const float cur = buf[off];
        bufb[off] = f2b(prev);
        prev = bd * prev + cur;
    }
    carry[tid] = prev;
}

// ---------------------------------------------------------------------------
// MFMA attention (as round 4).
// ---------------------------------------------------------------------------
__global__ __launch_bounds__(256) void attn_mfma_kernel(u16* __restrict__ qkvb,
                                                        const u16* __restrict__ kvstatesb) {
    const int b  = blockIdx.x;
    const int hb = b & 1;
    const int h  = (b >> 1) & 15;
    const int c  = b >> 5;
    const float slope = get_slope(h);
    const int t  = threadIdx.x;
    const int w  = t >> 6, l = t & 63;
    const int lg = l >> 4, lc = l & 15;
    const int giw = hb * 4 + w;
    const int i0  = giw << 5;

    __shared__ u16 Ks[32 * 128];
    __shared__ u16 Vt[128 * 40];
    __shared__ u16 Sb[4 * 1024];

    const u16* qbase = qkvb + (size_t)(c * BLKC) * QKV_STRIDE + h * HD;
    bf16x8 qa[2][4];
#pragma unroll
    for (int m = 0; m < 2; ++m)
#pragma unroll
        for (int kk = 0; kk < 4; ++kk)
            qa[m][kk] = *(const bf16x8*)(qbase +
                (size_t)(i0 + m * 16 + lc) * QKV_STRIDE + kk * 32 + lg * 8);

    f32x4 acc[2][8] = {};

    const u16* kbase = qkvb + (size_t)(c * BLKC) * QKV_STRIDE + HID + h * HD;
    const u16* vbase = kbase + HID;
    const int jtmax = hb * 4 + 4;
    const int ve  = t & 127;
    const int vph = t >> 7;
    u16* SbW = Sb + (w << 10);

    for (int jt = 0; jt < jtmax; ++jt) {
        __syncthreads();
#pragma unroll
        for (int u = 0; u < 2; ++u) {
            const int idx = t + (u << 8);
            const int j = idx >> 4, s = idx & 15;
            const int sp = s ^ (j & 7);
            GLOAD_LDS16(kbase + (size_t)(jt * 32 + j) * QKV_STRIDE + sp * 8,
                        Ks + idx * 8);
        }
        union { int4 q; u16 e[8]; } vv[2];
#pragma unroll
        for (int u = 0; u < 2; ++u) {
            const int p0 = vph * 8 + u * 16;
#pragma unroll
            for (int x = 0; x < 8; ++x) {
                const int p = p0 + x;
                const int j = ((p & 1) << 4) | (p >> 1);
                vv[u].e[x] = vbase[(size_t)(jt * 32 + j) * QKV_STRIDE + ve];
            }
        }
#pragma unroll
        for (int u = 0; u < 2; ++u) {
            const int p0 = vph * 8 + u * 16;
            *(int4*)&Vt[ve * 40 + p0] = vv[u].q;
        }
        __syncthreads();

        if (jt <= giw) {
            f32x4 sacc[2][2] = {};
#pragma unroll
            for (int kk = 0; kk < 4; ++kk) {
#pragma unroll
                for (int nj = 0; nj < 2; ++nj) {
                    const int j = nj * 16 + lc;
                    const int sp = (kk * 4 + lg) ^ (j & 7);
                    bf16x8 kf = *(const bf16x8*)&Ks[j * 128 + sp * 8];
#pragma unroll
                    for (int m = 0; m < 2; ++m)
                        sacc[m][nj] = __builtin_amdgcn_mfma_f32_16x16x32_bf16(
                            qa[m][kk], kf, sacc[m][nj], 0, 0, 0);
                }
            }
            const int di0 = i0 - jt * 32;
            const float cj0 = expf(slope * (float)lc);
            const float cj1 = expf(slope * (float)(16 + lc));
            const bool diag = (jt == giw);
#pragma unroll
            for (int m = 0; m < 2; ++m) {
#pragma unroll
                for (int r = 0; r < 4; ++r) {
                    const int irel = m * 16 + lg * 4 + r;
                    const float rex = expf(-slope * (float)(di0 + irel));
                    float v0 = sacc[m][0][r] * rex * cj0;
                    float v1 = sacc[m][1][r] * rex * cj1;
                    if (diag) {
                        if (irel < lc)      v0 = 0.f;
                        if (irel < 16 + lc) v1 = 0.f;
                    }
                    const u32 pk = pack2(v0, v1);
                    const int iL = irel;
                    const int rp = iL ^ ((iL >> 2) & 1);
                    *(u32*)&SbW[rp * 32 + ((lc << 1) ^ (((iL >> 2) & 3) << 3))] = pk;
                }
            }
            bf16x8 sA[2];
#pragma unroll
            for (int m = 0; m < 2; ++m) {
                const int iL = m * 16 + lc;
                const int rp = iL ^ ((iL >> 2) & 1);
                sA[m] = *(const bf16x8*)&SbW[rp * 32 + ((lg << 3) ^ (((iL >> 2) & 3) << 3))];
            }
#pragma unroll
            for (int ne = 0; ne < 8; ++ne) {
                bf16x8 vf = *(const bf16x8*)&Vt[(ne * 16 + lc) * 40 + lg * 8];
#pragma unroll
                for (int m = 0; m < 2; ++m)
                    acc[m][ne] = __builtin_amdgcn_mfma_f32_16x16x32_bf16(
                        sA[m], vf, acc[m][ne], 0, 0, 0);
            }
        }
    }

    const u16* kvpb = kvstatesb + (size_t)(c * NH + h) * (HD * HD);
    const float dR0 = expf(-slope * (float)(i0 + lc + 1));
    const float dR1 = expf(-slope * (float)(i0 + 16 + lc + 1));
#pragma unroll
    for (int kk = 0; kk < 4; ++kk) {
        bf16x8 qd[2];
#pragma unroll
        for (int m = 0; m < 2; ++m) {
            const float dR = m ? dR1 : dR0;
            union { bf16x8 v; u32 u[4]; } qq;
            const u16* qe = (const u16*)&qa[m][kk];
#pragma unroll
            for (int x = 0; x < 4; ++x)
                qq.u[x] = pack2(b2f(qe[2 * x]) * dR, b2f(qe[2 * x + 1]) * dR);
            qd[m] = qq.v;
        }
#pragma unroll
        for (int ne = 0; ne < 8; ++ne) {
            bf16x8 kv = *(const bf16x8*)(kvpb + (size_t)(ne * 16 + lc) * HD + kk * 32 + lg * 8);
#pragma unroll
            for (int m = 0; m < 2; ++m)
                acc[m][ne] = __builtin_amdgcn_mfma_f32_16x16x32_bf16(
                    qd[m], kv, acc[m][ne], 0, 0, 0);
        }
    }

    u16* ob = qkvb + (size_t)(c * BLKC) * QKV_STRIDE + h * HD;
#pragma unroll
    for (int m = 0; m < 2; ++m)
#pragma unroll
        for (int ne = 0; ne < 8; ++ne)
#pragma unroll
            for (int r = 0; r < 4; ++r)
                ob[(size_t)(i0 + m * 16 + lg * 4 + r) * QKV_STRIDE + ne * 16 + lc] =
                    f2b(acc[m][ne][r]);
}

// ---------------------------------------------------------------------------
// Group RMSNorm * g_norm_w * sigmoid(g): g read from gbuf (stride 2048).
// ---------------------------------------------------------------------------
__global__ __launch_bounds__(256) void gate_kernel(u16* __restrict__ qkvb,
                                                   const u16* __restrict__ gbuf,
                                                   const u16* __restrict__ gnw) {
    const int s = blockIdx.x;
    const int t = threadIdx.x;
    const int j = t << 3;
    const size_t base = (size_t)s * QKV_STRIDE;
    union { int4 v; u16 e[8]; } xr, gr, wv;
    xr.v = *(const int4*)(qkvb + base + j);
    gr.v = *(const int4*)(gbuf + (size_t)s * 2048 + j);
    wv.v = *(const int4*)(gnw + j);
    float x[8];
    float ss = 0.f;
#pragma unroll
    for (int i = 0; i < 8; ++i) { x[i] = b2f(xr.e[i]); ss += x[i] * x[i]; }
#pragma unroll
    for (int off = 16; off > 0; off >>= 1) ss += __shfl_xor(ss, off, 32);
    const float rstd = rsqrtf(ss * (1.f / 256.f) + EPSV);
    union { int4 v; u16 e[8]; } o;
#pragma unroll
    for (int i = 0; i < 8; ++i) {
        const float yv = x[i] * rstd * b2f(wv.e[i]) *
                         (1.f / (1.f + expf(-b2f(gr.e[i]))));
        o.e[i] = f2b(yv);
    }
    *(int4*)(qkvb + base + 2 * HID + j) = o.v;
}

// ---------------------------------------------------------------------------
extern "C" void kernel_launch(void* const* d_in, const int* in_sizes, int n_in,
                              void* d_out, int out_size, void* d_ws, size_t ws_size,
                              hipStream_t stream) {
    const int* pos = (const int*)d_in[1];
    float* out = (float*)d_out;   // reference output dtype: float32
    char* ws = (char*)d_ws;

    // ---- canonical bf16 input area -------------------------------------
    u16*  c_hs    = (u16*)(ws + 256);                 // 16777216 el
    u16*  c_qkvw  = c_hs   + 16777216;                // 12582912 el
    u16*  c_qkvb  = c_qkvw + 12582912;                // 6144
    u16*  c_qn    = c_qkvb + 6144;                    // 128
    u16*  c_kn    = c_qn   + 128;                     // 128
    u16*  c_gw    = c_kn   + 128;                     // 4194304
    u16*  c_gnw   = c_gw   + 4194304;                 // 2048
    u16*  c_dw    = c_gnw  + 2048;                    // 4194304
    const size_t canon_end = 256 + (size_t)2 * (16777216 + 12582912 + 6144 + 128 + 128 + 4194304 + 2048 + 4194304);
    const size_t work_off = (canon_end + 255) & ~(size_t)255;

    // ---- pick super-chunk size to fit ws -------------------------------
    const size_t MB = 1048576;
    int SCR;
    if      (ws_size >= work_off + 48 * MB) SCR = 2048;
    else if (ws_size >= work_off + 14 * MB) SCR = 512;
    else                                     SCR = 256;
    const int NCS = SCR / BLKC;
    const int NSC = S_LEN / SCR;

    u16*   qkvb    = (u16*)(ws + work_off);
    float* states  = (float*)(ws + work_off + (size_t)SCR * QKV_STRIDE * 2);
    float* carry   = states + (size_t)NCS * NH * HD * HD;
    u16*   statesb = (u16*)(carry + (size_t)NH * HD * HD);
    u16*   gbuf    = statesb + (size_t)NCS * NH * HD * HD;

    const dim3 B256(256);

    // 0) canonize all fp32 float inputs to bf16
    canonize_kernel<<<dim3(16777216 / 1024), B256, 0, stream>>>((const float*)d_in[0], c_hs,   16777216);
    canonize_kernel<<<dim3(12582912 / 1024), B256, 0, stream>>>((const float*)d_in[2], c_qkvw, 12582912);
    canonize_kernel<<<dim3(6),               B256, 0, stream>>>((const float*)d_in[3], c_qkvb, 6144);
    canonize_kernel<<<dim3(1),               B256, 0, stream>>>((const float*)d_in[4], c_qn,   128);
    canonize_kernel<<<dim3(1),               B256, 0, stream>>>((const float*)d_in[5], c_kn,   128);
    canonize_kernel<<<dim3(4194304 / 1024),  B256, 0, stream>>>((const float*)d_in[6], c_gw,   4194304);
    canonize_kernel<<<dim3(2),               B256, 0, stream>>>((const float*)d_in[7], c_gnw,  2048);
    canonize_kernel<<<dim3(4194304 / 1024),  B256, 0, stream>>>((const float*)d_in[8], c_dw,   4194304);

    hipMemsetAsync(carry, 0, (size_t)NH * HD * HD * sizeof(float), stream);

    for (int sc = 0; sc < NSC; ++sc) {
        const int row0 = sc * SCR;
        const u16* hsb = c_hs + (size_t)row0 * HID;
        // fused qkv + g GEMM (8-phase 256^2): N = 6144 qkv cols + 2048 g cols
        gemm256_fused<<<dim3(32, SCR / 256), dim3(512), 0, stream>>>(
            hsb, c_qkvw, c_gw, c_qkvb, qkvb, gbuf);
        normrope_kernel<<<dim3(SCR * NH / 4), B256, 0, stream>>>(
            qkvb, c_qn, c_kn, pos, row0);
        kv_contrib_kernel<<<dim3(NCS * NH * 2), B256, 0, stream>>>(qkvb, states);
        kv_scan_kernel<<<dim3(NH * HD * HD / 256), B256, 0, stream>>>(states, statesb, carry, NCS);
        attn_mfma_kernel<<<dim3(NCS * NH * 2), B256, 0, stream>>>(qkvb, statesb);
        gate_kernel<<<dim3(SCR), B256, 0, stream>>>(qkvb, gbuf, c_gnw);
        gemm_mfma<1><<<dim3(HID / 128, SCR / 128), B256, 0, stream>>>(
            qkvb + 2 * HID, c_dw, nullptr, out + (size_t)row0 * HID,
            HID, QKV_STRIDE, HID, HID);
    }
}

// Round 6
// 1010.106 us; speedup vs baseline: 5.1484x; 1.0096x over previous
//
#include <hip/hip_runtime.h>

#define S_LEN 8192
#define HID   2048
#define NH    16
#define HD    128
#define BLKC  256
#define QKV_STRIDE 6144
#define EPSV  1e-5f
#define SCALEF 0.08838834764831845f

typedef unsigned short u16;
typedef unsigned int   u32;
typedef __attribute__((ext_vector_type(8))) short bf16x8;
typedef __attribute__((ext_vector_type(4))) float f32x4;

__device__ __forceinline__ float b2f(u16 u) {
    unsigned int x = ((unsigned int)u) << 16;
    return __uint_as_float(x);
}
__device__ __forceinline__ u16 f2b(float f) {
    unsigned int u = __float_as_uint(f);
    u += 0x7fff + ((u >> 16) & 1);   // round-to-nearest-even
    return (u16)(u >> 16);
}
__device__ __forceinline__ u32 pack2(float lo, float hi) {
    return (u32)f2b(lo) | ((u32)f2b(hi) << 16);
}
__device__ __forceinline__ float get_slope(int h) {
    return exp2f(-0.5f * (float)(h + 1)) * 1.00001f;
}

#define GLOAD_LDS16(g, l)                                              \
    __builtin_amdgcn_global_load_lds(                                  \
        (const __attribute__((address_space(1))) void*)(g),            \
        (__attribute__((address_space(3))) void*)(l), 16, 0, 0)

// raw barrier with compiler memory fence (no vmcnt drain!)
#define BARF() do { asm volatile("" ::: "memory");                     \
                    __builtin_amdgcn_s_barrier();                      \
                    asm volatile("" ::: "memory"); } while (0)
#define VMW(n) asm volatile("s_waitcnt vmcnt(" #n ")" ::: "memory")

// ---------------------------------------------------------------------------
// Canonize one fp32 tensor to bf16.
// ---------------------------------------------------------------------------
__global__ __launch_bounds__(256) void canonize_kernel(const float* __restrict__ src,
                                                       u16* __restrict__ dst, int n) {
    const int i0 = (blockIdx.x * 256 + threadIdx.x) * 4;
    if (i0 >= n) return;
    const float4 f = *(const float4*)(src + i0);
    ushort4 o;
    o.x = f2b(f.x); o.y = f2b(f.y); o.z = f2b(f.z); o.w = f2b(f.w);
    *(ushort4*)(dst + i0) = o;
}

// ---------------------------------------------------------------------------
// 8-phase 256x256 fused GEMM: C = A[M][2048] @ concat(qkvw,gw)[8192][2048]^T.
// Swizzle: 16B-slot' = slot ^ ((row>>1)&3)  (64B rows -> rows spread all 8
// bank-quads; 2 lanes/quad = conflict-free). Applied on BOTH sides: staging
// source col pre-swizzled, fragment reads swizzled.
// MFMA operands SWAPPED (mfma(b,a)): lane holds 4 consecutive N-cols per
// fragment -> ushort4 epilogue stores.
// ---------------------------------------------------------------------------
template<int D, int KH, int MH>
__device__ __forceinline__ void rd_a(const u16* lds, int aoff0, bf16x8 af[4]) {
#pragma unroll
    for (int mm = 0; mm < 4; ++mm)
        af[mm] = *(const bf16x8*)&lds[D * 16384 + KH * 8192 + (MH * 4 + mm) * 512 + aoff0];
}
template<int D, int KH>
__device__ __forceinline__ void rd_b(const u16* lds, int boff0, bf16x8 bf[4]) {
#pragma unroll
    for (int nn = 0; nn < 4; ++nn)
        bf[nn] = *(const bf16x8*)&lds[32768 + D * 16384 + KH * 8192 + nn * 512 + boff0];
}
template<int MH>
__device__ __forceinline__ void mf(const bf16x8 af[4], const bf16x8 bf[4],
                                   f32x4 (&acc)[8][4]) {
    __builtin_amdgcn_s_setprio(1);
#pragma unroll
    for (int mm = 0; mm < 4; ++mm)
#pragma unroll
        for (int nn = 0; nn < 4; ++nn)
            acc[MH * 4 + mm][nn] = __builtin_amdgcn_mfma_f32_16x16x32_bf16(
                bf[nn], af[mm], acc[MH * 4 + mm][nn], 0, 0, 0);   // swapped
    __builtin_amdgcn_s_setprio(0);
}

__global__ __launch_bounds__(512, 2) void gemm256_fused(const u16* __restrict__ A,
                                                        const u16* __restrict__ qkvw,
                                                        const u16* __restrict__ gw,
                                                        const u16* __restrict__ bias,
                                                        u16* __restrict__ Cq,
                                                        u16* __restrict__ Cg) {
    __shared__ u16 lds[65536];          // 128 KiB: A at 0, B at 32768
    const int tid = threadIdx.x;
    const int w = tid >> 6, l = tid & 63;
    const int row0 = blockIdx.y << 8;
    const int col0 = blockIdx.x << 8;
    const bool isq = (blockIdx.x < 24);
    const u16* Bsel = isq ? qkvw : gw;
    const int bcol0 = isq ? col0 : (col0 - 6144);

    // staging: thread t -> LDS 16B slot t (row t>>2, phys slot t&3).
    // phys slot (t&3) holds logical slot (t&3)^((row>>1)&3) = (t&3)^((t>>3)&3)
    const int scol = (((tid & 3) ^ ((tid >> 3) & 3)) << 3);
    const u16* aSrc = A    + (size_t)(row0  + (tid >> 2)) * 2048 + scol;
    const u16* bSrc = Bsel + (size_t)(bcol0 + (tid >> 2)) * 2048 + scol;

#define STAGE_A(d, kh, tk) do {                                                        \
    GLOAD_LDS16(aSrc + (size_t)(tk) * 64 + (kh) * 32,                                  \
                lds + (d) * 16384 + (kh) * 8192 + tid * 8);                            \
    GLOAD_LDS16(aSrc + (size_t)128 * 2048 + (size_t)(tk) * 64 + (kh) * 32,             \
                lds + (d) * 16384 + (kh) * 8192 + 4096 + tid * 8); } while (0)
#define STAGE_B(d, kh, tk) do {                                                        \
    GLOAD_LDS16(bSrc + (size_t)(tk) * 64 + (kh) * 32,                                  \
                lds + 32768 + (d) * 16384 + (kh) * 8192 + tid * 8);                    \
    GLOAD_LDS16(bSrc + (size_t)128 * 2048 + (size_t)(tk) * 64 + (kh) * 32,             \
                lds + 32768 + (d) * 16384 + (kh) * 8192 + 4096 + tid * 8); } while (0)

    // fragment reads: row = 16*frag + (l&15) -> (row>>1)&3 = (l>>1)&3
    const int wr = (w >> 2) << 7;       // 0 / 128
    const int wc = (w & 3) << 6;        // 0 / 64 / 128 / 192
    const int fslot = ((((l >> 4) ^ (l >> 1)) & 3) << 3);
    const int aoff0 = (wr + (l & 15)) * 32 + fslot;
    const int boff0 = (wc + (l & 15)) * 32 + fslot;

    f32x4 acc[8][4] = {};
    bf16x8 af[4], bf[4];

    // prologue: kh0(0), kh1(0), kh0(1)  (6 stages = 12 loads)
    STAGE_A(0, 0, 0); STAGE_B(0, 0, 0);
    STAGE_A(0, 1, 0); STAGE_B(0, 1, 0);
    STAGE_A(1, 0, 1); STAGE_B(1, 0, 1);

    // main loop: tiles 0..29 (T=32), unrolled x2 for static buffer index
    for (int tk = 0; tk < 30; tk += 2) {
        // ---- tile tk (d=0) ----
        VMW(8); BARF();
        rd_a<0, 0, 0>(lds, aoff0, af); rd_b<0, 0>(lds, boff0, bf);
        STAGE_A(1, 1, tk + 1);
        BARF(); mf<0>(af, bf, acc);
        BARF();
        rd_a<0, 0, 1>(lds, aoff0, af);
        STAGE_B(1, 1, tk + 1);
        BARF(); mf<1>(af, bf, acc);
        VMW(8); BARF();
        rd_a<0, 1, 0>(lds, aoff0, af); rd_b<0, 1>(lds, boff0, bf);
        STAGE_A(0, 0, tk + 2);
        BARF(); mf<0>(af, bf, acc);
        BARF();
        rd_a<0, 1, 1>(lds, aoff0, af);
        STAGE_B(0, 0, tk + 2);
        BARF(); mf<1>(af, bf, acc);
        // ---- tile tk+1 (d=1) ----
        VMW(8); BARF();
        rd_a<1, 0, 0>(lds, aoff0, af); rd_b<1, 0>(lds, boff0, bf);
        STAGE_A(0, 1, tk + 2);
        BARF(); mf<0>(af, bf, acc);
        BARF();
        rd_a<1, 0, 1>(lds, aoff0, af);
        STAGE_B(0, 1, tk + 2);
        BARF(); mf<1>(af, bf, acc);
        VMW(8); BARF();
        rd_a<1, 1, 0>(lds, aoff0, af); rd_b<1, 1>(lds, boff0, bf);
        STAGE_A(1, 0, tk + 3);
        BARF(); mf<0>(af, bf, acc);
        BARF();
        rd_a<1, 1, 1>(lds, aoff0, af);
        STAGE_B(1, 0, tk + 3);
        BARF(); mf<1>(af, bf, acc);
    }
    // ---- tile 30 (d=0): stage only kh1(31) ----
    VMW(8); BARF();
    rd_a<0, 0, 0>(lds, aoff0, af); rd_b<0, 0>(lds, boff0, bf);
    STAGE_A(1, 1, 31);
    BARF(); mf<0>(af, bf, acc);
    BARF();
    rd_a<0, 0, 1>(lds, aoff0, af);
    STAGE_B(1, 1, 31);
    BARF(); mf<1>(af, bf, acc);
    VMW(8); BARF();
    rd_a<0, 1, 0>(lds, aoff0, af); rd_b<0, 1>(lds, boff0, bf);
    BARF(); mf<0>(af, bf, acc);
    BARF();
    rd_a<0, 1, 1>(lds, aoff0, af);
    BARF(); mf<1>(af, bf, acc);
    // ---- tile 31 (d=1): no stages ----
    VMW(4); BARF();
    rd_a<1, 0, 0>(lds, aoff0, af); rd_b<1, 0>(lds, boff0, bf);
    BARF(); mf<0>(af, bf, acc);
    BARF();
    rd_a<1, 0, 1>(lds, aoff0, af);
    BARF(); mf<1>(af, bf, acc);
    VMW(0); BARF();
    rd_a<1, 1, 0>(lds, aoff0, af); rd_b<1, 1>(lds, boff0, bf);
    BARF(); mf<0>(af, bf, acc);
    BARF();
    rd_a<1, 1, 1>(lds, aoff0, af);
    BARF(); mf<1>(af, bf, acc);
#undef STAGE_A
#undef STAGE_B

    // ---- epilogue (swapped layout): lane: row = base+(l&15) fixed,
    //      cols = base + (l>>4)*4 + 0..3 -> ushort4 store per fragment ----
    u16* Cout = isq ? Cq : Cg;
    const int ldc = isq ? 6144 : 2048;
    const int crb = row0 + wr + (l & 15);
    const int ccb = wc + ((l >> 4) << 2);          // col rel. to panel base
#pragma unroll
    for (int nn = 0; nn < 4; ++nn) {
        float bv[4] = {0.f, 0.f, 0.f, 0.f};
        if (isq) {
            ushort4 b4 = *(const ushort4*)(bias + col0 + ccb + nn * 16);
            bv[0] = b2f(b4.x); bv[1] = b2f(b4.y); bv[2] = b2f(b4.z); bv[3] = b2f(b4.w);
        }
#pragma unroll
        for (int mm = 0; mm < 8; ++mm) {
            ushort4 o;
            o.x = f2b(acc[mm][nn][0] + bv[0]);
            o.y = f2b(acc[mm][nn][1] + bv[1]);
            o.z = f2b(acc[mm][nn][2] + bv[2]);
            o.w = f2b(acc[mm][nn][3] + bv[3]);
            *(ushort4*)(Cout + (size_t)(crb + mm * 16) * ldc + bcol0 + ccb + nn * 16) = o;
        }
    }
}

// ---------------------------------------------------------------------------
// MFMA GEMM (128x128): C = A @ B^T (+bias). Swizzled LDS + swapped operands.
// ---------------------------------------------------------------------------
template<int OUT_F32>
__global__ __launch_bounds__(256) void gemm_mfma(const u16* __restrict__ A,
                                                 const u16* __restrict__ B,
                                                 const u16* __restrict__ bias,
                                                 void* __restrict__ Cv,
                                                 int K, int lda, int ldb, int ldc) {
    __shared__ u16 As[128 * 32];
    __shared__ u16 Bs[128 * 32];
    const int t = threadIdx.x;
    const int w = t >> 6;
    const int l = t & 63;
    const int row0 = blockIdx.y << 7, col0 = blockIdx.x << 7;

    // staging: thread t -> 16B slot t (row t>>2, phys slot t&3);
    // logical col = ((t&3)^((t>>3)&3))*8
    const int srow = t >> 2;
    const int scol = (((t & 3) ^ ((t >> 3) & 3)) << 3);
    const u16* Ap = A + (size_t)(row0 + srow) * lda + scol;
    const u16* Bp = B + (size_t)(col0 + srow) * ldb + scol;
    u16* AsP = As + t * 8;
    u16* BsP = Bs + t * 8;

    const int wr = (w >> 1) << 6;
    const int wc = (w & 1) << 6;
    const int fr = l & 15;
    const int fk = ((((l >> 4) ^ (l >> 1)) & 3) << 3);

    f32x4 acc[4][4] = {};

    for (int k0 = 0; k0 < K; k0 += 32) {
        __syncthreads();
        GLOAD_LDS16(Ap + k0, AsP);
        GLOAD_LDS16(Ap + k0 + (size_t)64 * lda, AsP + 64 * 32);
        GLOAD_LDS16(Bp + k0, BsP);
        GLOAD_LDS16(Bp + k0 + (size_t)64 * ldb, BsP + 64 * 32);
        __syncthreads();

        bf16x8 a[4], b[4];
#pragma unroll
        for (int m = 0; m < 4; ++m)
            a[m] = *(const bf16x8*)&As[(wr + (m << 4) + fr) * 32 + fk];
#pragma unroll
        for (int n = 0; n < 4; ++n)
            b[n] = *(const bf16x8*)&Bs[(wc + (n << 4) + fr) * 32 + fk];
#pragma unroll
        for (int m = 0; m < 4; ++m)
#pragma unroll
            for (int n = 0; n < 4; ++n)
                acc[m][n] = __builtin_amdgcn_mfma_f32_16x16x32_bf16(
                    b[n], a[m], acc[m][n], 0, 0, 0);   // swapped
        __syncthreads();
    }

    // swapped layout: row = row0+wr+m*16+(l&15); cols = col0+wc+n*16+(l>>4)*4+0..3
    const int crb = row0 + wr + (l & 15);
    const int ccb = col0 + wc + ((l >> 4) << 2);
#pragma unroll
    for (int n = 0; n < 4; ++n) {
        float bv[4] = {0.f, 0.f, 0.f, 0.f};
        if (bias != nullptr) {
            ushort4 b4 = *(const ushort4*)(bias + ccb + n * 16);
            bv[0] = b2f(b4.x); bv[1] = b2f(b4.y); bv[2] = b2f(b4.z); bv[3] = b2f(b4.w);
        }
#pragma unroll
        for (int m = 0; m < 4; ++m) {
            if (OUT_F32) {
                float4 o = make_float4(acc[m][n][0] + bv[0], acc[m][n][1] + bv[1],
                                       acc[m][n][2] + bv[2], acc[m][n][3] + bv[3]);
                *(float4*)((float*)Cv + (size_t)(crb + (m << 4)) * ldc + ccb + (n << 4)) = o;
            } else {
                ushort4 o;
                o.x = f2b(acc[m][n][0] + bv[0]); o.y = f2b(acc[m][n][1] + bv[1]);
                o.z = f2b(acc[m][n][2] + bv[2]); o.w = f2b(acc[m][n][3] + bv[3]);
                *(ushort4*)((u16*)Cv + (size_t)(crb + (m << 4)) * ldc + ccb + (n << 4)) = o;
            }
        }
    }
}

// ---------------------------------------------------------------------------
// Wave-per-(s,h): RMSNorm(q,k) -> RoPE -> q*=SCALE. In place. No LDS.
// ---------------------------------------------------------------------------
__global__ __launch_bounds__(256) void normrope_kernel(u16* __restrict__ qkvb,
                                                       const u16* __restrict__ qw,
                                                       const u16* __restrict__ kw,
                                                       const int* __restrict__ pos,
                                                       int row0) {
    const int wid = (blockIdx.x << 2) + (threadIdx.x >> 6);
    const int s = wid >> 4, h = wid & 15;
    const int l = threadIdx.x & 63;
    u16* qp = qkvb + (size_t)s * QKV_STRIDE + h * HD;
    u16* kp = qp + HID;
    const float q0 = b2f(qp[l]), q1 = b2f(qp[l + 64]);
    const float k0 = b2f(kp[l]), k1 = b2f(kp[l + 64]);
    float sq = q0 * q0 + q1 * q1;
    float sk = k0 * k0 + k1 * k1;
#pragma unroll
    for (int off = 32; off > 0; off >>= 1) {
        sq += __shfl_xor(sq, off);
        sk += __shfl_xor(sk, off);
    }
    const float qr = rsqrtf(sq * (1.f / 128.f) + EPSV);
    const float kr = rsqrtf(sk * (1.f / 128.f) + EPSV);
    const float nq0 = q0 * qr * b2f(qw[l]), nq1 = q1 * qr * b2f(qw[l + 64]);
    const float nk0 = k0 * kr * b2f(kw[l]), nk1 = k1 * kr * b2f(kw[l + 64]);
    const int p = pos[row0 + s];
    const float invf = powf(600000.f, -(float)l * (1.f / 64.f));
    const float fr = (float)p * invf;
    const float cs = cosf(fr), sn = sinf(fr);
    qp[l]      = f2b((nq0 * cs - nq1 * sn) * SCALEF);
    qp[l + 64] = f2b((nq1 * cs + nq0 * sn) * SCALEF);
    kp[l]      = f2b(nk0 * cs - nk1 * sn);
    kp[l + 64] = f2b(nk1 * cs + nk0 * sn);
}

// ---------------------------------------------------------------------------
// Per (local chunk, head, e-half): contribT[e][d] = sum_j kd[j] k[j][d] v[j][e]
// ---------------------------------------------------------------------------
__global__ __launch_bounds__(256) void kv_contrib_kernel(const u16* __restrict__ qkvb,
                                                         float* __restrict__ contrib) {
    const int b = blockIdx.x;
    const int eh = b & 1;
    const int h = (b >> 1) & 15;
    const int c = b >> 5;
    const float slope = get_slope(h);
    const u16* kb = qkvb + (size_t)c * BLKC * QKV_STRIDE + HID + h * HD;
    const u16* vb = kb + HID;
    const int t = threadIdx.x;
    const int tx = t & 15, ty = t >> 4;
    const int jj = t >> 5, dd = (t & 31) << 2;
    float acc[4][8] = {};
    __shared__ float kf[8][128], vf[8][128];
    for (int j0 = 0; j0 < BLKC; j0 += 8) {
        const float kd = expf(-slope * (float)(BLKC - 1 - (j0 + jj)));
        ushort4 k4 = *(const ushort4*)(kb + (size_t)(j0 + jj) * QKV_STRIDE + dd);
        ushort4 v4 = *(const ushort4*)(vb + (size_t)(j0 + jj) * QKV_STRIDE + dd);
        kf[jj][dd + 0] = b2f(k4.x) * kd; kf[jj][dd + 1] = b2f(k4.y) * kd;
        kf[jj][dd + 2] = b2f(k4.z) * kd; kf[jj][dd + 3] = b2f(k4.w) * kd;
        vf[jj][dd + 0] = b2f(v4.x); vf[jj][dd + 1] = b2f(v4.y);
        vf[jj][dd + 2] = b2f(v4.z); vf[jj][dd + 3] = b2f(v4.w);
        __syncthreads();
#pragma unroll
        for (int j = 0; j < 8; ++j) {
            float4 e0 = *(const float4*)&vf[j][(eh << 6) + (ty << 2)];
            float4 d0 = *(const float4*)&kf[j][tx << 3];
            float4 d1 = *(const float4*)&kf[j][(tx << 3) + 4];
            float er[4] = {e0.x, e0.y, e0.z, e0.w};
            float dr[8] = {d0.x, d0.y, d0.z, d0.w, d1.x, d1.y, d1.z, d1.w};
#pragma unroll
            for (int u = 0; u < 4; ++u)
#pragma unroll
                for (int v = 0; v < 8; ++v) acc[u][v] += er[u] * dr[v];
        }
        __syncthreads();
    }
    float* cb = contrib + ((size_t)(c * NH + h) * HD + (eh << 6) + (ty << 2)) * HD + (tx << 3);
#pragma unroll
    for (int u = 0; u < 4; ++u) {
        *(float4*)(cb + (size_t)u * HD)     = make_float4(acc[u][0], acc[u][1], acc[u][2], acc[u][3]);
        *(float4*)(cb + (size_t)u * HD + 4) = make_float4(acc[u][4], acc[u][5], acc[u][6], acc[u][7]);
    }
}

// ---------------------------------------------------------------------------
// Scan with carry across super-chunks; emits bf16 prefix states.
// ---------------------------------------------------------------------------
__global__ __launch_bounds__(256) void kv_scan_kernel(const float* __restrict__ buf,
                                                      u16* __restrict__ bufb,
                                                      float* __restrict__ carry,
                                                      int ncs) {
    const int tid = blockIdx.x * 256 + threadIdx.x;   // < NH*HD*HD = 262144
    const int h = tid >> 14;
    const float bd = expf(-get_slope(h) * (float)BLKC);
    float prev = carry[tid];
    for (int c = 0; c < ncs; ++c) {
        const size_t off = (size_t)c * (NH * HD * HD) + tid;
        const float cur = buf[off];
        bufb[off] = f2b(prev);
        prev = bd * prev + cur;
    }
    carry[tid] = prev;
}

// ---------------------------------------------------------------------------
// MFMA attention (unchanged from round 5).
// ---------------------------------------------------------------------------
__global__ __launch_bounds__(256) void attn_mfma_kernel(u16* __restrict__ qkvb,
                                                        const u16* __restrict__ kvstatesb) {
    const int b  = blockIdx.x;
    const int hb = b & 1;
    const int h  = (b >> 1) & 15;
    const int c  = b >> 5;
    const float slope = get_slope(h);
    const int t  = threadIdx.x;
    const int w  = t >> 6, l = t & 63;
    const int lg = l >> 4, lc = l & 15;
    const int giw = hb * 4 + w;
    const int i0  = giw << 5;

    __shared__ u16 Ks[32 * 128];
    __shared__ u16 Vt[128 * 40];
    __shared__ u16 Sb[4 * 1024];

    const u16* qbase = qkvb + (size_t)(c * BLKC) * QKV_STRIDE + h * HD;
    bf16x8 qa[2][4];
#pragma unroll
    for (int m = 0; m < 2; ++m)
#pragma unroll
        for (int kk = 0; kk < 4; ++kk)
            qa[m][kk] = *(const bf16x8*)(qbase +
                (size_t)(i0 + m * 16 + lc) * QKV_STRIDE + kk * 32 + lg * 8);

    f32x4 acc[2][8] = {};

    const u16* kbase = qkvb + (size_t)(c * BLKC) * QKV_STRIDE + HID + h * HD;
    const u16* vbase = kbase + HID;
    const int jtmax = hb * 4 + 4;
    const int ve  = t & 127;
    const int vph = t >> 7;
    u16* SbW = Sb + (w << 10);

    for (int jt = 0; jt < jtmax; ++jt) {
        __syncthreads();
#pragma unroll
        for (int u = 0; u < 2; ++u) {
            const int idx = t + (u << 8);
            const int j = idx >> 4, s = idx & 15;
            const int sp = s ^ (j & 7);
            GLOAD_LDS16(kbase + (size_t)(jt * 32 + j) * QKV_STRIDE + sp * 8,
                        Ks + idx * 8);
        }
        union { int4 q; u16 e[8]; } vv[2];
#pragma unroll
        for (int u = 0; u < 2; ++u) {
            const int p0 = vph * 8 + u * 16;
#pragma unroll
            for (int x = 0; x < 8; ++x) {
                const int p = p0 + x;
                const int j = ((p & 1) << 4) | (p >> 1);
                vv[u].e[x] = vbase[(size_t)(jt * 32 + j) * QKV_STRIDE + ve];
            }
        }
#pragma unroll
        for (int u = 0; u < 2; ++u) {
            const int p0 = vph * 8 + u * 16;
            *(int4*)&Vt[ve * 40 + p0] = vv[u].q;
        }
        __syncthreads();

        if (jt <= giw) {
            f32x4 sacc[2][2] = {};
#pragma unroll
            for (int kk = 0; kk < 4; ++kk) {
#pragma unroll
                for (int nj = 0; nj < 2; ++nj) {
                    const int j = nj * 16 + lc;
                    const int sp = (kk * 4 + lg) ^ (j & 7);
                    bf16x8 kf = *(const bf16x8*)&Ks[j * 128 + sp * 8];
#pragma unroll
                    for (int m = 0; m < 2; ++m)
                        sacc[m][nj] = __builtin_amdgcn_mfma_f32_16x16x32_bf16(
                            qa[m][kk], kf, sacc[m][nj], 0, 0, 0);
                }
            }
            const int di0 = i0 - jt * 32;
            const float cj0 = expf(slope * (float)lc);
            const float cj1 = expf(slope * (float)(16 + lc));
            const bool diag = (jt == giw);
#pragma unroll
            for (int m = 0; m < 2; ++m) {
#pragma unroll
                for (int r = 0; r < 4; ++r) {
                    const int irel = m * 16 + lg * 4 + r;
                    const float rex = expf(-slope * (float)(di0 + irel));
                    float v0 = sacc[m][0][r] * rex * cj0;
                    float v1 = sacc[m][1][r] * rex * cj1;
                    if (diag) {
                        if (irel < lc)      v0 = 0.f;
                        if (irel < 16 + lc) v1 = 0.f;
                    }
                    const u32 pk = pack2(v0, v1);
                    const int iL = irel;
                    const int rp = iL ^ ((iL >> 2) & 1);
                    *(u32*)&SbW[rp * 32 + ((lc << 1) ^ (((iL >> 2) & 3) << 3))] = pk;
                }
            }
            bf16x8 sA[2];
#pragma unroll
            for (int m = 0; m < 2; ++m) {
                const int iL = m * 16 + lc;
                const int rp = iL ^ ((iL >> 2) & 1);
                sA[m] = *(const bf16x8*)&SbW[rp * 32 + ((lg << 3) ^ (((iL >> 2) & 3) << 3))];
            }
#pragma unroll
            for (int ne = 0; ne < 8; ++ne) {
                bf16x8 vf = *(const bf16x8*)&Vt[(ne * 16 + lc) * 40 + lg * 8];
#pragma unroll
                for (int m = 0; m < 2; ++m)
                    acc[m][ne] = __builtin_amdgcn_mfma_f32_16x16x32_bf16(
                        sA[m], vf, acc[m][ne], 0, 0, 0);
            }
        }
    }

    const u16* kvpb = kvstatesb + (size_t)(c * NH + h) * (HD * HD);
    const float dR0 = expf(-slope * (float)(i0 + lc + 1));
    const float dR1 = expf(-slope * (float)(i0 + 16 + lc + 1));
#pragma unroll
    for (int kk = 0; kk < 4; ++kk) {
        bf16x8 qd[2];
#pragma unroll
        for (int m = 0; m < 2; ++m) {
            const float dR = m ? dR1 : dR0;
            union { bf16x8 v; u32 u[4]; } qq;
            const u16* qe = (const u16*)&qa[m][kk];
#pragma unroll
            for (int x = 0; x < 4; ++x)
                qq.u[x] = pack2(b2f(qe[2 * x]) * dR, b2f(qe[2 * x + 1]) * dR);
            qd[m] = qq.v;
        }
#pragma unroll
        for (int ne = 0; ne < 8; ++ne) {
            bf16x8 kv = *(const bf16x8*)(kvpb + (size_t)(ne * 16 + lc) * HD + kk * 32 + lg * 8);
#pragma unroll
            for (int m = 0; m < 2; ++m)
                acc[m][ne] = __builtin_amdgcn_mfma_f32_16x16x32_bf16(
                    qd[m], kv, acc[m][ne], 0, 0, 0);
        }
    }

    u16* ob = qkvb + (size_t)(c * BLKC) * QKV_STRIDE + h * HD;
#pragma unroll
    for (int m = 0; m < 2; ++m)
#pragma unroll
        for (int ne = 0; ne < 8; ++ne)
#pragma unroll
            for (int r = 0; r < 4; ++r)
                ob[(size_t)(i0 + m * 16 + lg * 4 + r) * QKV_STRIDE + ne * 16 + lc] =
                    f2b(acc[m][ne][r]);
}

// ---------------------------------------------------------------------------
// Group RMSNorm * g_norm_w * sigmoid(g): g read from gbuf (stride 2048).
// ---------------------------------------------------------------------------
__global__ __launch_bounds__(256) void gate_kernel(u16* __restrict__ qkvb,
                                                   const u16* __restrict__ gbuf,
                                                   const u16* __restrict__ gnw) {
    const int s = blockIdx.x;
    const int t = threadIdx.x;
    const int j = t << 3;
    const size_t base = (size_t)s * QKV_STRIDE;
    union { int4 v; u16 e[8]; } xr, gr, wv;
    xr.v = *(const int4*)(qkvb + base + j);
    gr.v = *(const int4*)(gbuf + (size_t)s * 2048 + j);
    wv.v = *(const int4*)(gnw + j);
    float x[8];
    float ss = 0.f;
#pragma unroll
    for (int i = 0; i < 8; ++i) { x[i] = b2f(xr.e[i]); ss += x[i] * x[i]; }
#pragma unroll
    for (int off = 16; off > 0; off >>= 1) ss += __shfl_xor(ss, off, 32);
    const float rstd = rsqrtf(ss * (1.f / 256.f) + EPSV);
    union { int4 v; u16 e[8]; } o;
#pragma unroll
    for (int i = 0; i < 8; ++i) {
        const float yv = x[i] * rstd * b2f(wv.e[i]) *
                         (1.f / (1.f + expf(-b2f(gr.e[i]))));
        o.e[i] = f2b(yv);
    }
    *(int4*)(qkvb + base + 2 * HID + j) = o.v;
}

// ---------------------------------------------------------------------------
extern "C" void kernel_launch(void* const* d_in, const int* in_sizes, int n_in,
                              void* d_out, int out_size, void* d_ws, size_t ws_size,
                              hipStream_t stream) {
    const int* pos = (const int*)d_in[1];
    float* out = (float*)d_out;   // reference output dtype: float32
    char* ws = (char*)d_ws;

    // ---- canonical bf16 input area -------------------------------------
    u16*  c_hs    = (u16*)(ws + 256);                 // 16777216 el
    u16*  c_qkvw  = c_hs   + 16777216;                // 12582912 el
    u16*  c_qkvb  = c_qkvw + 12582912;                // 6144
    u16*  c_qn    = c_qkvb + 6144;                    // 128
    u16*  c_kn    = c_qn   + 128;                     // 128
    u16*  c_gw    = c_kn   + 128;                     // 4194304
    u16*  c_gnw   = c_gw   + 4194304;                 // 2048
    u16*  c_dw    = c_gnw  + 2048;                    // 4194304
    const size_t canon_end = 256 + (size_t)2 * (16777216 + 12582912 + 6144 + 128 + 128 + 4194304 + 2048 + 4194304);
    const size_t work_off = (canon_end + 255) & ~(size_t)255;

    // ---- pick super-chunk size to fit ws -------------------------------
    const size_t MB = 1048576;
    int SCR;
    if      (ws_size >= work_off + 48 * MB) SCR = 2048;
    else if (ws_size >= work_off + 14 * MB) SCR = 512;
    else                                     SCR = 256;
    const int NCS = SCR / BLKC;
    const int NSC = S_LEN / SCR;

    u16*   qkvb    = (u16*)(ws + work_off);
    float* states  = (float*)(ws + work_off + (size_t)SCR * QKV_STRIDE * 2);
    float* carry   = states + (size_t)NCS * NH * HD * HD;
    u16*   statesb = (u16*)(carry + (size_t)NH * HD * HD);
    u16*   gbuf    = statesb + (size_t)NCS * NH * HD * HD;

    const dim3 B256(256);

    // 0) canonize all fp32 float inputs to bf16
    canonize_kernel<<<dim3(16777216 / 1024), B256, 0, stream>>>((const float*)d_in[0], c_hs,   16777216);
    canonize_kernel<<<dim3(12582912 / 1024), B256, 0, stream>>>((const float*)d_in[2], c_qkvw, 12582912);
    canonize_kernel<<<dim3(6),               B256, 0, stream>>>((const float*)d_in[3], c_qkvb, 6144);
    canonize_kernel<<<dim3(1),               B256, 0, stream>>>((const float*)d_in[4], c_qn,   128);
    canonize_kernel<<<dim3(1),               B256, 0, stream>>>((const float*)d_in[5], c_kn,   128);
    canonize_kernel<<<dim3(4194304 / 1024),  B256, 0, stream>>>((const float*)d_in[6], c_gw,   4194304);
    canonize_kernel<<<dim3(2),               B256, 0, stream>>>((const float*)d_in[7], c_gnw,  2048);
    canonize_kernel<<<dim3(4194304 / 1024),  B256, 0, stream>>>((const float*)d_in[8], c_dw,   4194304);

    hipMemsetAsync(carry, 0, (size_t)NH * HD * HD * sizeof(float), stream);

    for (int sc = 0; sc < NSC; ++sc) {
        const int row0 = sc * SCR;
        const u16* hsb = c_hs + (size_t)row0 * HID;
        // fused qkv + g GEMM (8-phase 256^2): N = 6144 qkv cols + 2048 g cols
        gemm256_fused<<<dim3(32, SCR / 256), dim3(512), 0, stream>>>(
            hsb, c_qkvw, c_gw, c_qkvb, qkvb, gbuf);
        normrope_kernel<<<dim3(SCR * NH / 4), B256, 0, stream>>>(
            qkvb, c_qn, c_kn, pos, row0);
        kv_contrib_kernel<<<dim3(NCS * NH * 2), B256, 0, stream>>>(qkvb, states);
        kv_scan_kernel<<<dim3(NH * HD * HD / 256), B256, 0, stream>>>(states, statesb, carry, NCS);
        attn_mfma_kernel<<<dim3(NCS * NH * 2), B256, 0, stream>>>(qkvb, statesb);
        gate_kernel<<<dim3(SCR), B256, 0, stream>>>(qkvb, gbuf, c_gnw);
        gemm_mfma<1><<<dim3(HID / 128, SCR / 128), B256, 0, stream>>>(
            qkvb + 2 * HID, c_dw, nullptr, out + (size_t)row0 * HID,
            HID, QKV_STRIDE, HID, HID);
    }
}

// Round 7
// 988.629 us; speedup vs baseline: 5.2602x; 1.0217x over previous
//
#include <hip/hip_runtime.h>

#define S_LEN 8192
#define HID   2048
#define NH    16
#define HD    128
#define BLKC  256
#define QKV_STRIDE 6144
#define EPSV  1e-5f
#define SCALEF 0.08838834764831845f

typedef unsigned short u16;
typedef unsigned int   u32;
typedef __attribute__((ext_vector_type(8))) short bf16x8;
typedef __attribute__((ext_vector_type(4))) float f32x4;

__device__ __forceinline__ float b2f(u16 u) {
    unsigned int x = ((unsigned int)u) << 16;
    return __uint_as_float(x);
}
__device__ __forceinline__ u16 f2b(float f) {
    unsigned int u = __float_as_uint(f);
    u += 0x7fff + ((u >> 16) & 1);   // round-to-nearest-even
    return (u16)(u >> 16);
}
__device__ __forceinline__ u32 pack2(float lo, float hi) {
    return (u32)f2b(lo) | ((u32)f2b(hi) << 16);
}
__device__ __forceinline__ float get_slope(int h) {
    return exp2f(-0.5f * (float)(h + 1)) * 1.00001f;
}

#define GLOAD_LDS16(g, l)                                              \
    __builtin_amdgcn_global_load_lds(                                  \
        (const __attribute__((address_space(1))) void*)(g),            \
        (__attribute__((address_space(3))) void*)(l), 16, 0, 0)

// raw barrier with compiler memory fence (no vmcnt drain!)
#define BARF() do { asm volatile("" ::: "memory");                     \
                    __builtin_amdgcn_s_barrier();                      \
                    asm volatile("" ::: "memory"); } while (0)
#define VMW(n) asm volatile("s_waitcnt vmcnt(" #n ")" ::: "memory")

// ---------------------------------------------------------------------------
// Canonize one fp32 tensor to bf16.
// ---------------------------------------------------------------------------
__global__ __launch_bounds__(256) void canonize_kernel(const float* __restrict__ src,
                                                       u16* __restrict__ dst, int n) {
    const int i0 = (blockIdx.x * 256 + threadIdx.x) * 4;
    if (i0 >= n) return;
    const float4 f = *(const float4*)(src + i0);
    ushort4 o;
    o.x = f2b(f.x); o.y = f2b(f.y); o.z = f2b(f.z); o.w = f2b(f.w);
    *(ushort4*)(dst + i0) = o;
}

// ---------------------------------------------------------------------------
// 256x256 fused GEMM: C = A[M][2048] @ concat(qkvw,gw)[8192][2048]^T.
// Phase = [VMW; BAR; rd_a+rd_b; stage_A; mf<0>; rd_a'; stage_B; mf<1>]:
// ONE barrier per half-tile (2 per K-tile). Per-wave lgkm waits before each
// wave's MFMAs drain its reads; the next phase-start barrier then makes the
// drain global before any stage writes the drained region. MFMA of one wave
// overlaps LDS reads/stage issue of others (inter-wave slip).
// Swizzle: 16B-slot' = slot ^ ((row>>1)&3) both-sides. Operands swapped
// (mfma(b,a)) -> lane holds 4 consecutive cols -> ushort4 stores.
// ---------------------------------------------------------------------------
template<int D, int KH, int MH>
__device__ __forceinline__ void rd_a(const u16* lds, int aoff0, bf16x8 af[4]) {
#pragma unroll
    for (int mm = 0; mm < 4; ++mm)
        af[mm] = *(const bf16x8*)&lds[D * 16384 + KH * 8192 + (MH * 4 + mm) * 512 + aoff0];
}
template<int D, int KH>
__device__ __forceinline__ void rd_b(const u16* lds, int boff0, bf16x8 bf[4]) {
#pragma unroll
    for (int nn = 0; nn < 4; ++nn)
        bf[nn] = *(const bf16x8*)&lds[32768 + D * 16384 + KH * 8192 + nn * 512 + boff0];
}
template<int MH>
__device__ __forceinline__ void mf(const bf16x8 af[4], const bf16x8 bf[4],
                                   f32x4 (&acc)[8][4]) {
    __builtin_amdgcn_s_setprio(1);
#pragma unroll
    for (int mm = 0; mm < 4; ++mm)
#pragma unroll
        for (int nn = 0; nn < 4; ++nn)
            acc[MH * 4 + mm][nn] = __builtin_amdgcn_mfma_f32_16x16x32_bf16(
                bf[nn], af[mm], acc[MH * 4 + mm][nn], 0, 0, 0);   // swapped
    __builtin_amdgcn_s_setprio(0);
}

__global__ __launch_bounds__(512, 2) void gemm256_fused(const u16* __restrict__ A,
                                                        const u16* __restrict__ qkvw,
                                                        const u16* __restrict__ gw,
                                                        const u16* __restrict__ bias,
                                                        u16* __restrict__ Cq,
                                                        u16* __restrict__ Cg) {
    __shared__ u16 lds[65536];          // 128 KiB: A at 0, B at 32768
    const int tid = threadIdx.x;
    const int w = tid >> 6, l = tid & 63;
    const int row0 = blockIdx.y << 8;
    const int col0 = blockIdx.x << 8;
    const bool isq = (blockIdx.x < 24);
    const u16* Bsel = isq ? qkvw : gw;
    const int bcol0 = isq ? col0 : (col0 - 6144);

    // staging: thread t -> LDS 16B slot t (row t>>2, phys slot t&3).
    // phys slot (t&3) holds logical slot (t&3)^((row>>1)&3) = (t&3)^((t>>3)&3)
    const int scol = (((tid & 3) ^ ((tid >> 3) & 3)) << 3);
    const u16* aSrc = A    + (size_t)(row0  + (tid >> 2)) * 2048 + scol;
    const u16* bSrc = Bsel + (size_t)(bcol0 + (tid >> 2)) * 2048 + scol;

#define STAGE_A(d, kh, tk) do {                                                        \
    GLOAD_LDS16(aSrc + (size_t)(tk) * 64 + (kh) * 32,                                  \
                lds + (d) * 16384 + (kh) * 8192 + tid * 8);                            \
    GLOAD_LDS16(aSrc + (size_t)128 * 2048 + (size_t)(tk) * 64 + (kh) * 32,             \
                lds + (d) * 16384 + (kh) * 8192 + 4096 + tid * 8); } while (0)
#define STAGE_B(d, kh, tk) do {                                                        \
    GLOAD_LDS16(bSrc + (size_t)(tk) * 64 + (kh) * 32,                                  \
                lds + 32768 + (d) * 16384 + (kh) * 8192 + tid * 8);                    \
    GLOAD_LDS16(bSrc + (size_t)128 * 2048 + (size_t)(tk) * 64 + (kh) * 32,             \
                lds + 32768 + (d) * 16384 + (kh) * 8192 + 4096 + tid * 8); } while (0)

    // fragment reads: row = 16*frag + (l&15) -> (row>>1)&3 = (l>>1)&3
    const int wr = (w >> 2) << 7;       // 0 / 128
    const int wc = (w & 3) << 6;        // 0 / 64 / 128 / 192
    const int fslot = ((((l >> 4) ^ (l >> 1)) & 3) << 3);
    const int aoff0 = (wr + (l & 15)) * 32 + fslot;
    const int boff0 = (wc + (l & 15)) * 32 + fslot;

    f32x4 acc[8][4] = {};
    bf16x8 af[4], bf[4];

    // prologue: kh0(0), kh1(0), kh0(1)  (6 stages = 12 loads)
    STAGE_A(0, 0, 0); STAGE_B(0, 0, 0);
    STAGE_A(0, 1, 0); STAGE_B(0, 1, 0);
    STAGE_A(1, 0, 1); STAGE_B(1, 0, 1);

    // main loop: tiles 0..29 (T=32), unrolled x2 for static buffer index
    for (int tk = 0; tk < 30; tk += 2) {
        // ---- tile tk (d=0), kh=0 ----
        VMW(8); BARF();
        rd_a<0, 0, 0>(lds, aoff0, af); rd_b<0, 0>(lds, boff0, bf);
        STAGE_A(1, 1, tk + 1);
        mf<0>(af, bf, acc);
        rd_a<0, 0, 1>(lds, aoff0, af);
        STAGE_B(1, 1, tk + 1);
        mf<1>(af, bf, acc);
        // ---- tile tk (d=0), kh=1 ----
        VMW(8); BARF();
        rd_a<0, 1, 0>(lds, aoff0, af); rd_b<0, 1>(lds, boff0, bf);
        STAGE_A(0, 0, tk + 2);
        mf<0>(af, bf, acc);
        rd_a<0, 1, 1>(lds, aoff0, af);
        STAGE_B(0, 0, tk + 2);
        mf<1>(af, bf, acc);
        // ---- tile tk+1 (d=1), kh=0 ----
        VMW(8); BARF();
        rd_a<1, 0, 0>(lds, aoff0, af); rd_b<1, 0>(lds, boff0, bf);
        STAGE_A(0, 1, tk + 2);
        mf<0>(af, bf, acc);
        rd_a<1, 0, 1>(lds, aoff0, af);
        STAGE_B(0, 1, tk + 2);
        mf<1>(af, bf, acc);
        // ---- tile tk+1 (d=1), kh=1 ----
        VMW(8); BARF();
        rd_a<1, 1, 0>(lds, aoff0, af); rd_b<1, 1>(lds, boff0, bf);
        STAGE_A(1, 0, tk + 3);
        mf<0>(af, bf, acc);
        rd_a<1, 1, 1>(lds, aoff0, af);
        STAGE_B(1, 0, tk + 3);
        mf<1>(af, bf, acc);
    }
    // ---- tile 30 (d=0), kh=0: stage (1,1,31) ----
    VMW(8); BARF();
    rd_a<0, 0, 0>(lds, aoff0, af); rd_b<0, 0>(lds, boff0, bf);
    STAGE_A(1, 1, 31);
    mf<0>(af, bf, acc);
    rd_a<0, 0, 1>(lds, aoff0, af);
    STAGE_B(1, 1, 31);
    mf<1>(af, bf, acc);
    // ---- tile 30 (d=0), kh=1 ----
    VMW(8); BARF();
    rd_a<0, 1, 0>(lds, aoff0, af); rd_b<0, 1>(lds, boff0, bf);
    mf<0>(af, bf, acc);
    rd_a<0, 1, 1>(lds, aoff0, af);
    mf<1>(af, bf, acc);
    // ---- tile 31 (d=1), kh=0 ----
    VMW(4); BARF();
    rd_a<1, 0, 0>(lds, aoff0, af); rd_b<1, 0>(lds, boff0, bf);
    mf<0>(af, bf, acc);
    rd_a<1, 0, 1>(lds, aoff0, af);
    mf<1>(af, bf, acc);
    // ---- tile 31 (d=1), kh=1 ----
    VMW(0); BARF();
    rd_a<1, 1, 0>(lds, aoff0, af); rd_b<1, 1>(lds, boff0, bf);
    mf<0>(af, bf, acc);
    rd_a<1, 1, 1>(lds, aoff0, af);
    mf<1>(af, bf, acc);
#undef STAGE_A
#undef STAGE_B

    // ---- epilogue (swapped layout): lane: row = base+(l&15) fixed,
    //      cols = base + (l>>4)*4 + 0..3 -> ushort4 store per fragment ----
    u16* Cout = isq ? Cq : Cg;
    const int ldc = isq ? 6144 : 2048;
    const int crb = row0 + wr + (l & 15);
    const int ccb = wc + ((l >> 4) << 2);          // col rel. to panel base
#pragma unroll
    for (int nn = 0; nn < 4; ++nn) {
        float bv[4] = {0.f, 0.f, 0.f, 0.f};
        if (isq) {
            ushort4 b4 = *(const ushort4*)(bias + col0 + ccb + nn * 16);
            bv[0] = b2f(b4.x); bv[1] = b2f(b4.y); bv[2] = b2f(b4.z); bv[3] = b2f(b4.w);
        }
#pragma unroll
        for (int mm = 0; mm < 8; ++mm) {
            ushort4 o;
            o.x = f2b(acc[mm][nn][0] + bv[0]);
            o.y = f2b(acc[mm][nn][1] + bv[1]);
            o.z = f2b(acc[mm][nn][2] + bv[2]);
            o.w = f2b(acc[mm][nn][3] + bv[3]);
            *(ushort4*)(Cout + (size_t)(crb + mm * 16) * ldc + bcol0 + ccb + nn * 16) = o;
        }
    }
}

// ---------------------------------------------------------------------------
// MFMA GEMM (128x128): C = A @ B^T (+bias). Swizzled LDS + swapped operands.
// ---------------------------------------------------------------------------
template<int OUT_F32>
__global__ __launch_bounds__(256) void gemm_mfma(const u16* __restrict__ A,
                                                 const u16* __restrict__ B,
                                                 const u16* __restrict__ bias,
                                                 void* __restrict__ Cv,
                                                 int K, int lda, int ldb, int ldc) {
    __shared__ u16 As[128 * 32];
    __shared__ u16 Bs[128 * 32];
    const int t = threadIdx.x;
    const int w = t >> 6;
    const int l = t & 63;
    const int row0 = blockIdx.y << 7, col0 = blockIdx.x << 7;

    const int srow = t >> 2;
    const int scol = (((t & 3) ^ ((t >> 3) & 3)) << 3);
    const u16* Ap = A + (size_t)(row0 + srow) * lda + scol;
    const u16* Bp = B + (size_t)(col0 + srow) * ldb + scol;
    u16* AsP = As + t * 8;
    u16* BsP = Bs + t * 8;

    const int wr = (w >> 1) << 6;
    const int wc = (w & 1) << 6;
    const int fr = l & 15;
    const int fk = ((((l >> 4) ^ (l >> 1)) & 3) << 3);

    f32x4 acc[4][4] = {};

    for (int k0 = 0; k0 < K; k0 += 32) {
        __syncthreads();
        GLOAD_LDS16(Ap + k0, AsP);
        GLOAD_LDS16(Ap + k0 + (size_t)64 * lda, AsP + 64 * 32);
        GLOAD_LDS16(Bp + k0, BsP);
        GLOAD_LDS16(Bp + k0 + (size_t)64 * ldb, BsP + 64 * 32);
        __syncthreads();

        bf16x8 a[4], b[4];
#pragma unroll
        for (int m = 0; m < 4; ++m)
            a[m] = *(const bf16x8*)&As[(wr + (m << 4) + fr) * 32 + fk];
#pragma unroll
        for (int n = 0; n < 4; ++n)
            b[n] = *(const bf16x8*)&Bs[(wc + (n << 4) + fr) * 32 + fk];
#pragma unroll
        for (int m = 0; m < 4; ++m)
#pragma unroll
            for (int n = 0; n < 4; ++n)
                acc[m][n] = __builtin_amdgcn_mfma_f32_16x16x32_bf16(
                    b[n], a[m], acc[m][n], 0, 0, 0);   // swapped
        __syncthreads();
    }

    const int crb = row0 + wr + (l & 15);
    const int ccb = col0 + wc + ((l >> 4) << 2);
#pragma unroll
    for (int n = 0; n < 4; ++n) {
        float bv[4] = {0.f, 0.f, 0.f, 0.f};
        if (bias != nullptr) {
            ushort4 b4 = *(const ushort4*)(bias + ccb + n * 16);
            bv[0] = b2f(b4.x); bv[1] = b2f(b4.y); bv[2] = b2f(b4.z); bv[3] = b2f(b4.w);
        }
#pragma unroll
        for (int m = 0; m < 4; ++m) {
            if (OUT_F32) {
                float4 o = make_float4(acc[m][n][0] + bv[0], acc[m][n][1] + bv[1],
                                       acc[m][n][2] + bv[2], acc[m][n][3] + bv[3]);
                *(float4*)((float*)Cv + (size_t)(crb + (m << 4)) * ldc + ccb + (n << 4)) = o;
            } else {
                ushort4 o;
                o.x = f2b(acc[m][n][0] + bv[0]); o.y = f2b(acc[m][n][1] + bv[1]);
                o.z = f2b(acc[m][n][2] + bv[2]); o.w = f2b(acc[m][n][3] + bv[3]);
                *(ushort4*)((u16*)Cv + (size_t)(crb + (m << 4)) * ldc + ccb + (n << 4)) = o;
            }
        }
    }
}

// ---------------------------------------------------------------------------
// Wave-per-(s,h): RMSNorm(q,k) -> RoPE -> q*=SCALE. In place. No LDS.
// ---------------------------------------------------------------------------
__global__ __launch_bounds__(256) void normrope_kernel(u16* __restrict__ qkvb,
                                                       const u16* __restrict__ qw,
                                                       const u16* __restrict__ kw,
                                                       const int* __restrict__ pos,
                                                       int row0) {
    const int wid = (blockIdx.x << 2) + (threadIdx.x >> 6);
    const int s = wid >> 4, h = wid & 15;
    const int l = threadIdx.x & 63;
    u16* qp = qkvb + (size_t)s * QKV_STRIDE + h * HD;
    u16* kp = qp + HID;
    const float q0 = b2f(qp[l]), q1 = b2f(qp[l + 64]);
    const float k0 = b2f(kp[l]), k1 = b2f(kp[l + 64]);
    float sq = q0 * q0 + q1 * q1;
    float sk = k0 * k0 + k1 * k1;
#pragma unroll
    for (int off = 32; off > 0; off >>= 1) {
        sq += __shfl_xor(sq, off);
        sk += __shfl_xor(sk, off);
    }
    const float qr = rsqrtf(sq * (1.f / 128.f) + EPSV);
    const float kr = rsqrtf(sk * (1.f / 128.f) + EPSV);
    const float nq0 = q0 * qr * b2f(qw[l]), nq1 = q1 * qr * b2f(qw[l + 64]);
    const float nk0 = k0 * kr * b2f(kw[l]), nk1 = k1 * kr * b2f(kw[l + 64]);
    const int p = pos[row0 + s];
    const float invf = powf(600000.f, -(float)l * (1.f / 64.f));
    const float fr = (float)p * invf;
    const float cs = cosf(fr), sn = sinf(fr);
    qp[l]      = f2b((nq0 * cs - nq1 * sn) * SCALEF);
    qp[l + 64] = f2b((nq1 * cs + nq0 * sn) * SCALEF);
    kp[l]      = f2b(nk0 * cs - nk1 * sn);
    kp[l + 64] = f2b(nk1 * cs + nk0 * sn);
}

// ---------------------------------------------------------------------------
// Per (local chunk, head, e-half): contribT[e][d] = sum_j kd[j] k[j][d] v[j][e]
// ---------------------------------------------------------------------------
__global__ __launch_bounds__(256) void kv_contrib_kernel(const u16* __restrict__ qkvb,
                                                         float* __restrict__ contrib) {
    const int b = blockIdx.x;
    const int eh = b & 1;
    const int h = (b >> 1) & 15;
    const int c = b >> 5;
    const float slope = get_slope(h);
    const u16* kb = qkvb + (size_t)c * BLKC * QKV_STRIDE + HID + h * HD;
    const u16* vb = kb + HID;
    const int t = threadIdx.x;
    const int tx = t & 15, ty = t >> 4;
    const int jj = t >> 5, dd = (t & 31) << 2;
    float acc[4][8] = {};
    __shared__ float kf[8][128], vf[8][128];
    for (int j0 = 0; j0 < BLKC; j0 += 8) {
        const float kd = expf(-slope * (float)(BLKC - 1 - (j0 + jj)));
        ushort4 k4 = *(const ushort4*)(kb + (size_t)(j0 + jj) * QKV_STRIDE + dd);
        ushort4 v4 = *(const ushort4*)(vb + (size_t)(j0 + jj) * QKV_STRIDE + dd);
        kf[jj][dd + 0] = b2f(k4.x) * kd; kf[jj][dd + 1] = b2f(k4.y) * kd;
        kf[jj][dd + 2] = b2f(k4.z) * kd; kf[jj][dd + 3] = b2f(k4.w) * kd;
        vf[jj][dd + 0] = b2f(v4.x); vf[jj][dd + 1] = b2f(v4.y);
        vf[jj][dd + 2] = b2f(v4.z); vf[jj][dd + 3] = b2f(v4.w);
        __syncthreads();
#pragma unroll
        for (int j = 0; j < 8; ++j) {
            float4 e0 = *(const float4*)&vf[j][(eh << 6) + (ty << 2)];
            float4 d0 = *(const float4*)&kf[j][tx << 3];
            float4 d1 = *(const float4*)&kf[j][(tx << 3) + 4];
            float er[4] = {e0.x, e0.y, e0.z, e0.w};
            float dr[8] = {d0.x, d0.y, d0.z, d0.w, d1.x, d1.y, d1.z, d1.w};
#pragma unroll
            for (int u = 0; u < 4; ++u)
#pragma unroll
                for (int v = 0; v < 8; ++v) acc[u][v] += er[u] * dr[v];
        }
        __syncthreads();
    }
    float* cb = contrib + ((size_t)(c * NH + h) * HD + (eh << 6) + (ty << 2)) * HD + (tx << 3);
#pragma unroll
    for (int u = 0; u < 4; ++u) {
        *(float4*)(cb + (size_t)u * HD)     = make_float4(acc[u][0], acc[u][1], acc[u][2], acc[u][3]);
        *(float4*)(cb + (size_t)u * HD + 4) = make_float4(acc[u][4], acc[u][5], acc[u][6], acc[u][7]);
    }
}

// ---------------------------------------------------------------------------
// Scan with carry across super-chunks; emits bf16 prefix states.
// ---------------------------------------------------------------------------
__global__ __launch_bounds__(256) void kv_scan_kernel(const float* __restrict__ buf,
                                                      u16* __restrict__ bufb,
                                                      float* __restrict__ carry,
                                                      int ncs) {
    const int tid = blockIdx.x * 256 + threadIdx.x;   // < NH*HD*HD = 262144
    const int h = tid >> 14;
    const float bd = expf(-get_slope(h) * (float)BLKC);
    float prev = carry[tid];
    for (int c = 0; c < ncs; ++c) {
        const size_t off = (size_t)c * (NH * HD * HD) + tid;
        const float cur = buf[off];
        bufb[off] = f2b(prev);
        prev = bd * prev + cur;
    }
    carry[tid] = prev;
}

// ---------------------------------------------------------------------------
// MFMA attention (unchanged).
// ---------------------------------------------------------------------------
__global__ __launch_bounds__(256) void attn_mfma_kernel(u16* __restrict__ qkvb,
                                                        const u16* __restrict__ kvstatesb) {
    const int b  = blockIdx.x;
    const int hb = b & 1;
    const int h  = (b >> 1) & 15;
    const int c  = b >> 5;
    const float slope = get_slope(h);
    const int t  = threadIdx.x;
    const int w  = t >> 6, l = t & 63;
    const int lg = l >> 4, lc = l & 15;
    const int giw = hb * 4 + w;
    const int i0  = giw << 5;

    __shared__ u16 Ks[32 * 128];
    __shared__ u16 Vt[128 * 40];
    __shared__ u16 Sb[4 * 1024];

    const u16* qbase = qkvb + (size_t)(c * BLKC) * QKV_STRIDE + h * HD;
    bf16x8 qa[2][4];
#pragma unroll
    for (int m = 0; m < 2; ++m)
#pragma unroll
        for (int kk = 0; kk < 4; ++kk)
            qa[m][kk] = *(const bf16x8*)(qbase +
                (size_t)(i0 + m * 16 + lc) * QKV_STRIDE + kk * 32 + lg * 8);

    f32x4 acc[2][8] = {};

    const u16* kbase = qkvb + (size_t)(c * BLKC) * QKV_STRIDE + HID + h * HD;
    const u16* vbase = kbase + HID;
    const int jtmax = hb * 4 + 4;
    const int ve  = t & 127;
    const int vph = t >> 7;
    u16* SbW = Sb + (w << 10);

    for (int jt = 0; jt < jtmax; ++jt) {
        __syncthreads();
#pragma unroll
        for (int u = 0; u < 2; ++u) {
            const int idx = t + (u << 8);
            const int j = idx >> 4, s = idx & 15;
            const int sp = s ^ (j & 7);
            GLOAD_LDS16(kbase + (size_t)(jt * 32 + j) * QKV_STRIDE + sp * 8,
                        Ks + idx * 8);
        }
        union { int4 q; u16 e[8]; } vv[2];
#pragma unroll
        for (int u = 0; u < 2; ++u) {
            const int p0 = vph * 8 + u * 16;
#pragma unroll
            for (int x = 0; x < 8; ++x) {
                const int p = p0 + x;
                const int j = ((p & 1) << 4) | (p >> 1);
                vv[u].e[x] = vbase[(size_t)(jt * 32 + j) * QKV_STRIDE + ve];
            }
        }
#pragma unroll
        for (int u = 0; u < 2; ++u) {
            const int p0 = vph * 8 + u * 16;
            *(int4*)&Vt[ve * 40 + p0] = vv[u].q;
        }
        __syncthreads();

        if (jt <= giw) {
            f32x4 sacc[2][2] = {};
#pragma unroll
            for (int kk = 0; kk < 4; ++kk) {
#pragma unroll
                for (int nj = 0; nj < 2; ++nj) {
                    const int j = nj * 16 + lc;
                    const int sp = (kk * 4 + lg) ^ (j & 7);
                    bf16x8 kf = *(const bf16x8*)&Ks[j * 128 + sp * 8];
#pragma unroll
                    for (int m = 0; m < 2; ++m)
                        sacc[m][nj] = __builtin_amdgcn_mfma_f32_16x16x32_bf16(
                            qa[m][kk], kf, sacc[m][nj], 0, 0, 0);
                }
            }
            const int di0 = i0 - jt * 32;
            const float cj0 = expf(slope * (float)lc);
            const float cj1 = expf(slope * (float)(16 + lc));
            const bool diag = (jt == giw);
#pragma unroll
            for (int m = 0; m < 2; ++m) {
#pragma unroll
                for (int r = 0; r < 4; ++r) {
                    const int irel = m * 16 + lg * 4 + r;
                    const float rex = expf(-slope * (float)(di0 + irel));
                    float v0 = sacc[m][0][r] * rex * cj0;
                    float v1 = sacc[m][1][r] * rex * cj1;
                    if (diag) {
                        if (irel < lc)      v0 = 0.f;
                        if (irel < 16 + lc) v1 = 0.f;
                    }
                    const u32 pk = pack2(v0, v1);
                    const int iL = irel;
                    const int rp = iL ^ ((iL >> 2) & 1);
                    *(u32*)&SbW[rp * 32 + ((lc << 1) ^ (((iL >> 2) & 3) << 3))] = pk;
                }
            }
            bf16x8 sA[2];
#pragma unroll
            for (int m = 0; m < 2; ++m) {
                const int iL = m * 16 + lc;
                const int rp = iL ^ ((iL >> 2) & 1);
                sA[m] = *(const bf16x8*)&SbW[rp * 32 + ((lg << 3) ^ (((iL >> 2) & 3) << 3))];
            }
#pragma unroll
            for (int ne = 0; ne < 8; ++ne) {
                bf16x8 vf = *(const bf16x8*)&Vt[(ne * 16 + lc) * 40 + lg * 8];
#pragma unroll
                for (int m = 0; m < 2; ++m)
                    acc[m][ne] = __builtin_amdgcn_mfma_f32_16x16x32_bf16(
                        sA[m], vf, acc[m][ne], 0, 0, 0);
            }
        }
    }

    const u16* kvpb = kvstatesb + (size_t)(c * NH + h) * (HD * HD);
    const float dR0 = expf(-slope * (float)(i0 + lc + 1));
    const float dR1 = expf(-slope * (float)(i0 + 16 + lc + 1));
#pragma unroll
    for (int kk = 0; kk < 4; ++kk) {
        bf16x8 qd[2];
#pragma unroll
        for (int m = 0; m < 2; ++m) {
            const float dR = m ? dR1 : dR0;
            union { bf16x8 v; u32 u[4]; } qq;
            const u16* qe = (const u16*)&qa[m][kk];
#pragma unroll
            for (int x = 0; x < 4; ++x)
                qq.u[x] = pack2(b2f(qe[2 * x]) * dR, b2f(qe[2 * x + 1]) * dR);
            qd[m] = qq.v;
        }
#pragma unroll
        for (int ne = 0; ne < 8; ++ne) {
            bf16x8 kv = *(const bf16x8*)(kvpb + (size_t)(ne * 16 + lc) * HD + kk * 32 + lg * 8);
#pragma unroll
            for (int m = 0; m < 2; ++m)
                acc[m][ne] = __builtin_amdgcn_mfma_f32_16x16x32_bf16(
                    qd[m], kv, acc[m][ne], 0, 0, 0);
        }
    }

    u16* ob = qkvb + (size_t)(c * BLKC) * QKV_STRIDE + h * HD;
#pragma unroll
    for (int m = 0; m < 2; ++m)
#pragma unroll
        for (int ne = 0; ne < 8; ++ne)
#pragma unroll
            for (int r = 0; r < 4; ++r)
                ob[(size_t)(i0 + m * 16 + lg * 4 + r) * QKV_STRIDE + ne * 16 + lc] =
                    f2b(acc[m][ne][r]);
}

// ---------------------------------------------------------------------------
// Group RMSNorm * g_norm_w * sigmoid(g): g read from gbuf (stride 2048).
// ---------------------------------------------------------------------------
__global__ __launch_bounds__(256) void gate_kernel(u16* __restrict__ qkvb,
                                                   const u16* __restrict__ gbuf,
                                                   const u16* __restrict__ gnw) {
    const int s = blockIdx.x;
    const int t = threadIdx.x;
    const int j = t << 3;
    const size_t base = (size_t)s * QKV_STRIDE;
    union { int4 v; u16 e[8]; } xr, gr, wv;
    xr.v = *(const int4*)(qkvb + base + j);
    gr.v = *(const int4*)(gbuf + (size_t)s * 2048 + j);
    wv.v = *(const int4*)(gnw + j);
    float x[8];
    float ss = 0.f;
#pragma unroll
    for (int i = 0; i < 8; ++i) { x[i] = b2f(xr.e[i]); ss += x[i] * x[i]; }
#pragma unroll
    for (int off = 16; off > 0; off >>= 1) ss += __shfl_xor(ss, off, 32);
    const float rstd = rsqrtf(ss * (1.f / 256.f) + EPSV);
    union { int4 v; u16 e[8]; } o;
#pragma unroll
    for (int i = 0; i < 8; ++i) {
        const float yv = x[i] * rstd * b2f(wv.e[i]) *
                         (1.f / (1.f + expf(-b2f(gr.e[i]))));
        o.e[i] = f2b(yv);
    }
    *(int4*)(qkvb + base + 2 * HID + j) = o.v;
}

// ---------------------------------------------------------------------------
extern "C" void kernel_launch(void* const* d_in, const int* in_sizes, int n_in,
                              void* d_out, int out_size, void* d_ws, size_t ws_size,
                              hipStream_t stream) {
    const int* pos = (const int*)d_in[1];
    float* out = (float*)d_out;   // reference output dtype: float32
    char* ws = (char*)d_ws;

    // ---- canonical bf16 input area -------------------------------------
    u16*  c_hs    = (u16*)(ws + 256);                 // 16777216 el
    u16*  c_qkvw  = c_hs   + 16777216;                // 12582912 el
    u16*  c_qkvb  = c_qkvw + 12582912;                // 6144
    u16*  c_qn    = c_qkvb + 6144;                    // 128
    u16*  c_kn    = c_qn   + 128;                     // 128
    u16*  c_gw    = c_kn   + 128;                     // 4194304
    u16*  c_gnw   = c_gw   + 4194304;                 // 2048
    u16*  c_dw    = c_gnw  + 2048;                    // 4194304
    const size_t canon_end = 256 + (size_t)2 * (16777216 + 12582912 + 6144 + 128 + 128 + 4194304 + 2048 + 4194304);
    const size_t work_off = (canon_end + 255) & ~(size_t)255;

    // ---- pick super-chunk size to fit ws -------------------------------
    const size_t MB = 1048576;
    int SCR;
    if      (ws_size >= work_off + 48 * MB) SCR = 2048;
    else if (ws_size >= work_off + 14 * MB) SCR = 512;
    else                                     SCR = 256;
    const int NCS = SCR / BLKC;
    const int NSC = S_LEN / SCR;

    u16*   qkvb    = (u16*)(ws + work_off);
    float* states  = (float*)(ws + work_off + (size_t)SCR * QKV_STRIDE * 2);
    float* carry   = states + (size_t)NCS * NH * HD * HD;
    u16*   statesb = (u16*)(carry + (size_t)NH * HD * HD);
    u16*   gbuf    = statesb + (size_t)NCS * NH * HD * HD;

    const dim3 B256(256);

    // 0) canonize all fp32 float inputs to bf16
    canonize_kernel<<<dim3(16777216 / 1024), B256, 0, stream>>>((const float*)d_in[0], c_hs,   16777216);
    canonize_kernel<<<dim3(12582912 / 1024), B256, 0, stream>>>((const float*)d_in[2], c_qkvw, 12582912);
    canonize_kernel<<<dim3(6),               B256, 0, stream>>>((const float*)d_in[3], c_qkvb, 6144);
    canonize_kernel<<<dim3(1),               B256, 0, stream>>>((const float*)d_in[4], c_qn,   128);
    canonize_kernel<<<dim3(1),               B256, 0, stream>>>((const float*)d_in[5], c_kn,   128);
    canonize_kernel<<<dim3(4194304 / 1024),  B256, 0, stream>>>((const float*)d_in[6], c_gw,   4194304);
    canonize_kernel<<<dim3(2),               B256, 0, stream>>>((const float*)d_in[7], c_gnw,  2048);
    canonize_kernel<<<dim3(4194304 / 1024),  B256, 0, stream>>>((const float*)d_in[8], c_dw,   4194304);

    hipMemsetAsync(carry, 0, (size_t)NH * HD * HD * sizeof(float), stream);

    for (int sc = 0; sc < NSC; ++sc) {
        const int row0 = sc * SCR;
        const u16* hsb = c_hs + (size_t)row0 * HID;
        // fused qkv + g GEMM (256^2): N = 6144 qkv cols + 2048 g cols
        gemm256_fused<<<dim3(32, SCR / 256), dim3(512), 0, stream>>>(
            hsb, c_qkvw, c_gw, c_qkvb, qkvb, gbuf);
        normrope_kernel<<<dim3(SCR * NH / 4), B256, 0, stream>>>(
            qkvb, c_qn, c_kn, pos, row0);
        kv_contrib_kernel<<<dim3(NCS * NH * 2), B256, 0, stream>>>(qkvb, states);
        kv_scan_kernel<<<dim3(NH * HD * HD / 256), B256, 0, stream>>>(states, statesb, carry, NCS);
        attn_mfma_kernel<<<dim3(NCS * NH * 2), B256, 0, stream>>>(qkvb, statesb);
        gate_kernel<<<dim3(SCR), B256, 0, stream>>>(qkvb, gbuf, c_gnw);
        gemm_mfma<1><<<dim3(HID / 128, SCR / 128), B256, 0, stream>>>(
            qkvb + 2 * HID, c_dw, nullptr, out + (size_t)row0 * HID,
            HID, QKV_STRIDE, HID, HID);
    }
}